// Round 17
// baseline (1053.493 us; speedup 1.0000x reference)
//
#include <hip/hip_runtime.h>
#include <hip/hip_bf16.h>
#include <cstdio>

#define HID 256

using short8  = __attribute__((ext_vector_type(8))) short;
using floatx4 = __attribute__((ext_vector_type(4))) float;

typedef const unsigned int __attribute__((address_space(1)))* as1_cuintp;
typedef unsigned int __attribute__((address_space(3)))* as3_uintp;

__device__ inline unsigned short bf16_rn(float x) {
    unsigned u = __float_as_uint(x);
    return (unsigned short)((u + 0x7FFFu + ((u >> 16) & 1u)) >> 16);
}
__device__ inline float bf2f(unsigned short u) {
    return __uint_as_float(((unsigned)u) << 16);
}

// ---------------- diagnostic marker (ws too small) ----------------
__global__ void marker_k(float* __restrict__ out, int n, float v) {
    int i = blockIdx.x * blockDim.x + threadIdx.x;
    if (i < n) out[i] = v;
}

// ---------------- int64-vs-int32 detection ----------------
__global__ void detect64_k(const unsigned* __restrict__ eiw, int E,
                           const unsigned* __restrict__ bw, int Nh,
                           int* __restrict__ any_nonzero) {
    int total = E + Nh;
    unsigned loc = 0;
    for (int i = blockIdx.x * blockDim.x + threadIdx.x; i < total;
         i += gridDim.x * blockDim.x) {
        loc |= (i < E) ? eiw[2 * i + 1] : bw[2 * (i - E) + 1];
    }
    if (loc) atomicOr(any_nonzero, 1);
}

__global__ void norm_idx_k(const int* __restrict__ src, int* __restrict__ dst,
                           int n, const int* __restrict__ any_nonzero) {
    int is64 = (any_nonzero[0] == 0);
    for (int i = blockIdx.x * blockDim.x + threadIdx.x; i < n;
         i += gridDim.x * blockDim.x) {
        dst[i] = is64 ? src[2 * i] : src[i];
    }
}

// ---------------- graph boundaries (batch is sorted) ----------------
__global__ void pool_bounds_k(const int* __restrict__ batch, int N, int G,
                              int* __restrict__ starts) {
    int g = blockIdx.x * blockDim.x + threadIdx.x;
    if (g > G) return;
    int lo = 0, hi = N;
    while (lo < hi) {
        int mid = (lo + hi) >> 1;
        if (batch[mid] < g) lo = mid + 1; else hi = mid;
    }
    starts[g] = lo;
}

// ---------------- CSR build ----------------
__global__ void deg_count_k(const int* __restrict__ ei, int E, int N,
                            int* __restrict__ deg) {
    int e = blockIdx.x * blockDim.x + threadIdx.x;
    if (e >= E) return;
    int s = ei[e];
    int d = ei[E + e];
    if ((unsigned)s >= (unsigned)N || (unsigned)d >= (unsigned)N) return;
    atomicAdd(&deg[d], 1);
}

// ---- two-level grid-wide exclusive scan ----
#define SCAN_BLK 256

__global__ __launch_bounds__(SCAN_BLK) void scan_a_k(const int* __restrict__ deg,
                                                     int* __restrict__ bsum, int N) {
    __shared__ int red[SCAN_BLK];
    int i = blockIdx.x * SCAN_BLK + threadIdx.x;
    int v = (i < N) ? deg[i] : 0;
    red[threadIdx.x] = v;
    __syncthreads();
#pragma unroll
    for (int off = SCAN_BLK / 2; off > 0; off >>= 1) {
        if (threadIdx.x < off) red[threadIdx.x] += red[threadIdx.x + off];
        __syncthreads();
    }
    if (threadIdx.x == 0) bsum[blockIdx.x] = red[0];
}

__global__ __launch_bounds__(1024) void scan_b_k(int* __restrict__ bsum, int nb) {
    __shared__ int tsum[1024];
    int t = threadIdx.x;
    int v = (t < nb) ? bsum[t] : 0;
    tsum[t] = v;
    __syncthreads();
    for (int off = 1; off < 1024; off <<= 1) {
        int u = (t >= off) ? tsum[t - off] : 0;
        __syncthreads();
        tsum[t] += u;
        __syncthreads();
    }
    if (t < nb) bsum[t] = tsum[t] - v;
}

__global__ __launch_bounds__(SCAN_BLK) void scan_c_k(const int* __restrict__ deg,
                                                     const int* __restrict__ bsum,
                                                     int* __restrict__ row_ptr, int N) {
    __shared__ int tsum[SCAN_BLK];
    int t = threadIdx.x;
    int i = blockIdx.x * SCAN_BLK + t;
    int v = (i < N) ? deg[i] : 0;
    tsum[t] = v;
    __syncthreads();
    for (int off = 1; off < SCAN_BLK; off <<= 1) {
        int u = (t >= off) ? tsum[t - off] : 0;
        __syncthreads();
        tsum[t] += u;
        __syncthreads();
    }
    if (i <= N) row_ptr[i] = tsum[t] - v + bsum[blockIdx.x];
}

__global__ __launch_bounds__(1024) void scan_rowptr_k(const int* __restrict__ deg,
                                                      int* __restrict__ row_ptr, int N) {
    __shared__ int tsum[1024];
    int t = threadIdx.x;
    int chunk = (N + 1023) / 1024;
    int lo = t * chunk;
    int hi = min(lo + chunk, N);
    int s = 0;
    for (int i = lo; i < hi; i++) s += deg[i];
    tsum[t] = s;
    __syncthreads();
    for (int off = 1; off < 1024; off <<= 1) {
        int v = (t >= off) ? tsum[t - off] : 0;
        __syncthreads();
        tsum[t] += v;
        __syncthreads();
    }
    int run = (t == 0) ? 0 : tsum[t - 1];
    for (int i = lo; i < hi; i++) { row_ptr[i] = run; run += deg[i]; }
    if (hi >= N && lo <= N) row_ptr[N] = run;
}

__global__ void fill_csr_k(const int* __restrict__ ei, int E, int N,
                           const int* __restrict__ row_ptr, int* __restrict__ cursor,
                           int* __restrict__ esrc) {
    int e = blockIdx.x * blockDim.x + threadIdx.x;
    if (e >= E) return;
    int s = ei[e];
    int d = ei[E + e];
    if ((unsigned)s >= (unsigned)N || (unsigned)d >= (unsigned)N) return;
    int pos = atomicAdd(&cursor[d], 1);
    esrc[row_ptr[d] + pos] = s;
}

// ---------------- gather aggregation, 28-wide (layer 1) ----------------
__global__ void gather28_k(const float* __restrict__ x, const int* __restrict__ row_ptr,
                           const int* __restrict__ esrc, float* __restrict__ Q28, int N) {
    int gid = blockIdx.x * blockDim.x + threadIdx.x;
    int node = gid >> 5;
    if (node >= N) return;
    int lane = gid & 31;
    if (lane >= 28) return;
    int s = row_ptr[node], e = row_ptr[node + 1];
    float acc = 0.f;
    for (int i = s; i < e; i++) {
        int src = esrc[i];
        acc += x[(size_t)src * 28 + lane];
    }
    Q28[(size_t)node * 28 + lane] = acc;
}

// ---------------- layer 1 fused: P = relu(agg28@Wrel.T + x@Wroot.T + b) ----------------
__global__ __launch_bounds__(256) void l1_fused_k(
    const float* __restrict__ x, const float* __restrict__ agg,
    const float* __restrict__ Wrel, const float* __restrict__ Wroot,
    const float* __restrict__ bias, float* __restrict__ out, int M) {
    __shared__ float As[64][28];
    __shared__ float Xs[64][28];
    int t = threadIdx.x;
    int n0 = blockIdx.x * 64;
    float wrel[28], wroot[28];
#pragma unroll
    for (int k = 0; k < 28; k++) {
        wrel[k]  = Wrel[t * 28 + k];
        wroot[k] = Wroot[t * 28 + k];
    }
    float b = bias[t];
    for (int idx = t; idx < 64 * 28; idx += 256) {
        int r = idx / 28;
        int c = idx - r * 28;
        int gr = n0 + r;
        As[r][c] = (gr < M) ? agg[(size_t)gr * 28 + c] : 0.f;
        Xs[r][c] = (gr < M) ? x[(size_t)gr * 28 + c] : 0.f;
    }
    __syncthreads();
    int nmax = min(64, M - n0);
    for (int n = 0; n < nmax; n++) {
        float acc = b;
#pragma unroll
        for (int k4 = 0; k4 < 28; k4 += 4) {
            float4 a  = *(const float4*)&As[n][k4];
            float4 xx = *(const float4*)&Xs[n][k4];
            acc += a.x * wrel[k4] + a.y * wrel[k4 + 1] + a.z * wrel[k4 + 2] + a.w * wrel[k4 + 3];
            acc += xx.x * wroot[k4] + xx.y * wroot[k4 + 1] + xx.z * wroot[k4 + 2] + xx.w * wroot[k4 + 3];
        }
        out[(size_t)(n0 + n) * HID + t] = fmaxf(acc, 0.f);
    }
}

// ---------------- weight split: chunk-major, global-load-lds-ready layout ----------------
// Per matrix (131072 ushorts): [ch 0..7][plane 0..1][col 0..255][gp 0..3][e 0..7]
// gp = sg ^ ((col>>1)&3). Staging copies one 16KB plane linearly; reads XOR.
__global__ void wsplit6_k(const float* W0, const float* W1, const float* W2,
                          const float* W3, const float* W4, const float* W5,
                          unsigned short* __restrict__ out_hl, int n) {
    int i = blockIdx.x * blockDim.x + threadIdx.x;
    if (i >= n) return;
    const float* W = (blockIdx.y == 0) ? W0 : (blockIdx.y == 1) ? W1 :
                     (blockIdx.y == 2) ? W2 : (blockIdx.y == 3) ? W3 :
                     (blockIdx.y == 4) ? W4 : W5;
    unsigned short* o = out_hl + (size_t)blockIdx.y * 131072;
    float a = W[i];
    unsigned short h = bf16_rn(a);
    unsigned short lo = bf16_rn(a - bf2f(h));
    int col = i >> 8;            // out-feature row of W
    int k   = i & 255;
    int ch  = k >> 5;
    int sg  = (k >> 3) & 3;
    int e   = k & 7;
    int gp  = sg ^ ((col >> 1) & 3);
    size_t base = (size_t)ch * 16384 + (size_t)col * 32 + gp * 8 + e;
    o[base] = h;                 // plane 0 (hi)
    o[base + 8192] = lo;         // plane 1 (lo)
}

// ---------------- fused gather+GEMM strip kernel ----------------
// Pout[strip] = relu(AGG(Pin)@Wr.T + Pin@Wo.T + bias), AGG = CSR edge-sum.
// 64-row strip, 256 thr, 4 waves; wave w owns cols [w*64,+64). Phase-1 A-staging
// computes the aggregation k-slice on the fly (sum of Pin[src] slices); phase-2
// stages Pin[row] (root). W pipeline: single-plane LDS + wave-private hi->lo swap
// via global_load_lds (round-16 structure, 126us measured).
#define LSTR 40

__global__ __launch_bounds__(256) void gemm_fused_k(
    const int* __restrict__ row_ptr, const int* __restrict__ esrc,
    const float* __restrict__ Pin, const unsigned short* __restrict__ Wr_hl,
    float* __restrict__ Pout, const unsigned short* __restrict__ Wo_hl,
    const float* __restrict__ bias, int M) {
    __shared__ __attribute__((aligned(16))) unsigned short Ah[64 * LSTR];  // 5 KB
    __shared__ __attribute__((aligned(16))) unsigned short Al[64 * LSTR];  // 5 KB
    __shared__ __attribute__((aligned(16))) unsigned short Wbuf[8192];     // 16 KB
    int t = threadIdx.x;
    int brow = blockIdx.x * 64;
    int w = t >> 6;
    int l = t & 63;

    floatx4 acc[4][4];
#pragma unroll
    for (int i = 0; i < 4; i++)
#pragma unroll
        for (int j = 0; j < 4; j++) acc[i][j] = (floatx4){0.f, 0.f, 0.f, 0.f};

    int srow = t >> 2;       // 0..63 (row within strip this thread stages)
    int sg   = t & 3;        // k-granule of 8
    int gr   = brow + srow;
    int es = 0, ee = 0;
    if (gr < M) { es = row_ptr[gr]; ee = row_ptr[gr + 1]; }

    for (int ch = 0; ch < 16; ch++) {
        int phase2 = (ch >= 8);
        const unsigned short* Whl = phase2 ? Wo_hl : Wr_hl;
        int kbase = (ch & 7) * 32;

        // ---- issue Wh (plane 0), own wave slice: 4 x 1KB via global_load_lds ----
        {
            const char* wg = (const char*)(Whl + (size_t)(ch & 7) * 16384) + w * 4096;
            char* ld = (char*)Wbuf + w * 4096;
#pragma unroll
            for (int i = 0; i < 4; i++) {
                __builtin_amdgcn_global_load_lds(
                    (as1_cuintp)(const void*)(wg + i * 1024 + l * 16),
                    (as3_uintp)(void*)(ld + i * 1024),
                    16, 0, 0);
            }
        }
        // ---- stage A k-slice: phase1 = edge-sum of Pin rows; phase2 = Pin row ----
        {
            float v[8] = {0.f, 0.f, 0.f, 0.f, 0.f, 0.f, 0.f, 0.f};
            if (gr < M) {
                if (!phase2) {
                    for (int i = es; i < ee; i++) {
                        int src = esrc[i];
                        const float* pr = Pin + (size_t)src * HID + kbase + sg * 8;
                        float4 u0 = *(const float4*)pr;
                        float4 u1 = *(const float4*)(pr + 4);
                        v[0] += u0.x; v[1] += u0.y; v[2] += u0.z; v[3] += u0.w;
                        v[4] += u1.x; v[5] += u1.y; v[6] += u1.z; v[7] += u1.w;
                    }
                } else {
                    const float* pr = Pin + (size_t)gr * HID + kbase + sg * 8;
                    float4 u0 = *(const float4*)pr;
                    float4 u1 = *(const float4*)(pr + 4);
                    v[0] = u0.x; v[1] = u0.y; v[2] = u0.z; v[3] = u0.w;
                    v[4] = u1.x; v[5] = u1.y; v[6] = u1.z; v[7] = u1.w;
                }
            }
            union { unsigned short us[8]; short8 v8; } hh, ll;
#pragma unroll
            for (int j = 0; j < 8; j++) {
                unsigned short h = bf16_rn(v[j]);
                float hf = __uint_as_float(((unsigned)h) << 16);
                hh.us[j] = h;
                ll.us[j] = bf16_rn(v[j] - hf);
            }
            int base = srow * LSTR + sg * 8;
            *(short8*)(Ah + base) = hh.v8;
            *(short8*)(Al + base) = ll.v8;
        }
        __syncthreads();   // A staged + (implicit vmcnt0) Wh landed

        // ---- fragments ----
        int frow = l & 15;
        int fg   = l >> 4;
        short8 ahf[4], alf[4], wf[4];
#pragma unroll
        for (int rt = 0; rt < 4; rt++) {
            int base = (rt * 16 + frow) * LSTR + fg * 8;
            ahf[rt] = *(short8*)(Ah + base);
            alf[rt] = *(short8*)(Al + base);
        }
#pragma unroll
        for (int ct = 0; ct < 4; ct++) {
            int col = w * 64 + ct * 16 + frow;
            int gp = fg ^ ((col >> 1) & 3);
            wf[ct] = *(short8*)(Wbuf + col * 32 + gp * 8);
        }
        // all our LDS reads must complete before overwriting own W slice
        asm volatile("s_waitcnt lgkmcnt(0)" ::: "memory");
        __builtin_amdgcn_sched_barrier(0);
        // ---- issue Wl (plane 1) into the same wave-private slice ----
        {
            const char* wg = (const char*)(Whl + (size_t)(ch & 7) * 16384 + 8192) + w * 4096;
            char* ld = (char*)Wbuf + w * 4096;
#pragma unroll
            for (int i = 0; i < 4; i++) {
                __builtin_amdgcn_global_load_lds(
                    (as1_cuintp)(const void*)(wg + i * 1024 + l * 16),
                    (as3_uintp)(void*)(ld + i * 1024),
                    16, 0, 0);
            }
        }
        // ---- 32 MFMA with Wh (hides Wl latency): Ah*Wh + Al*Wh ----
#pragma unroll
        for (int rt = 0; rt < 4; rt++)
#pragma unroll
            for (int ct = 0; ct < 4; ct++) {
                acc[rt][ct] = __builtin_amdgcn_mfma_f32_16x16x32_bf16(
                    ahf[rt], wf[ct], acc[rt][ct], 0, 0, 0);
                acc[rt][ct] = __builtin_amdgcn_mfma_f32_16x16x32_bf16(
                    alf[rt], wf[ct], acc[rt][ct], 0, 0, 0);
            }
        // ---- wave-local wait for Wl, then 16 MFMA: Ah*Wl ----
        asm volatile("s_waitcnt vmcnt(0)" ::: "memory");
        __builtin_amdgcn_sched_barrier(0);
#pragma unroll
        for (int ct = 0; ct < 4; ct++) {
            int col = w * 64 + ct * 16 + frow;
            int gp = fg ^ ((col >> 1) & 3);
            wf[ct] = *(short8*)(Wbuf + col * 32 + gp * 8);
        }
#pragma unroll
        for (int rt = 0; rt < 4; rt++)
#pragma unroll
            for (int ct = 0; ct < 4; ct++)
                acc[rt][ct] = __builtin_amdgcn_mfma_f32_16x16x32_bf16(
                    ahf[rt], wf[ct], acc[rt][ct], 0, 0, 0);
        __syncthreads();   // before next chunk overwrites Ah/Al
    }

    // ---- epilogue: relu(acc+bias) -> Pout (out-of-place, no hazards) ----
#pragma unroll
    for (int ct = 0; ct < 4; ct++) {
        int gc = w * 64 + ct * 16 + (l & 15);
        float bs = bias[gc];
#pragma unroll
        for (int rt = 0; rt < 4; rt++) {
            floatx4 a = acc[rt][ct];
#pragma unroll
            for (int r = 0; r < 4; r++) {
                int orow = brow + rt * 16 + (l >> 4) * 4 + r;
                if (orow < M)
                    Pout[(size_t)orow * HID + gc] = fmaxf(a[r] + bs, 0.f);
            }
        }
    }
}

// ---------------- per-layer mean-pool slice ----------------
__global__ __launch_bounds__(256) void pool_slice_k(const float* __restrict__ xl,
                                                    const int* __restrict__ starts,
                                                    float* __restrict__ gslice, int N) {
    int g = blockIdx.x;
    int t = threadIdx.x;
    int s = starts[g], e = starts[g + 1];
    s = max(0, min(s, N));
    e = max(s, min(e, N));
    float a = 0.f;
    for (int n = s; n < e; n++) a += xl[(size_t)n * HID + t];
    float inv = 1.f / (float)max(e - s, 1);
    gslice[(size_t)g * 1024 + t] = a * inv;
}

// ---------------- out-of-place dual GEMM (MLP head, fp32) ----------------
#define BM 64
#define BN 64
#define BK 32
#define LP 68

__global__ __launch_bounds__(256) void gemm_dual_k(
    const float* __restrict__ A1, int lda1, const float* __restrict__ W1,
    const float* __restrict__ A2, int lda2, const float* __restrict__ W2,
    const float* __restrict__ bias, float* __restrict__ out, int ldout,
    int M, int K1, int K2, int relu) {
    __shared__ float As[BK][LP];
    __shared__ float Ws[BK][LP];
    int t = threadIdx.x;
    int brow = blockIdx.x * BM;
    int bcol = blockIdx.y * BN;
    int tx = t & 15, ty = t >> 4;
    float acc[4][4] = {{0.f}};
    int Ktot = K1 + K2;
    int srow = t >> 3;
    int sk4 = (t & 7) << 2;

    for (int kk = 0; kk < Ktot; kk += BK) {
        int phase2 = (kk >= K1);
        const float* A = phase2 ? A2 : A1;
        const float* W = phase2 ? W2 : W1;
        int lda = phase2 ? lda2 : lda1;
        int ldw = phase2 ? K2 : K1;
        int kbase = phase2 ? (kk - K1) : kk;
#pragma unroll
        for (int i = 0; i < 2; i++) {
            int r = srow + i * 32;
            int gr = brow + r;
            float4 v = make_float4(0.f, 0.f, 0.f, 0.f);
            if (gr < M) v = *(const float4*)(A + (size_t)gr * lda + kbase + sk4);
            As[sk4 + 0][r] = v.x; As[sk4 + 1][r] = v.y;
            As[sk4 + 2][r] = v.z; As[sk4 + 3][r] = v.w;
            float4 w = *(const float4*)(W + (size_t)(bcol + r) * ldw + kbase + sk4);
            Ws[sk4 + 0][r] = w.x; Ws[sk4 + 1][r] = w.y;
            Ws[sk4 + 2][r] = w.z; Ws[sk4 + 3][r] = w.w;
        }
        __syncthreads();
#pragma unroll
        for (int k = 0; k < BK; k++) {
            float4 a = *(const float4*)&As[k][ty << 2];
            float4 w = *(const float4*)&Ws[k][tx << 2];
            float av[4] = {a.x, a.y, a.z, a.w};
            float wv[4] = {w.x, w.y, w.z, w.w};
#pragma unroll
            for (int i = 0; i < 4; i++)
#pragma unroll
                for (int j = 0; j < 4; j++)
                    acc[i][j] = fmaf(av[i], wv[j], acc[i][j]);
        }
        __syncthreads();
    }
#pragma unroll
    for (int i = 0; i < 4; i++) {
        int gr = brow + (ty << 2) + i;
        if (gr >= M) continue;
#pragma unroll
        for (int j = 0; j < 4; j++) {
            int gc = bcol + (tx << 2) + j;
            float v = acc[i][j] + bias[gc];
            if (relu) v = fmaxf(v, 0.f);
            out[(size_t)gr * ldout + gc] = v;
        }
    }
}

// ---------------- fc4 ----------------
__global__ void fc4_k(const float* __restrict__ in, const float* __restrict__ w,
                      const float* __restrict__ b, float* __restrict__ out, int M) {
    int gid = blockIdx.x * blockDim.x + threadIdx.x;
    int row = gid >> 6;
    if (row >= M) return;
    int lane = gid & 63;
    float4 v  = *(const float4*)(in + (size_t)row * HID + lane * 4);
    float4 ww = *(const float4*)(w + lane * 4);
    float acc = v.x * ww.x + v.y * ww.y + v.z * ww.z + v.w * ww.w;
#pragma unroll
    for (int off = 32; off; off >>= 1) acc += __shfl_down(acc, off);
    if (lane == 0) out[row] = acc + b[0];
}

extern "C" void kernel_launch(void* const* d_in, const int* in_sizes, int n_in,
                              void* d_out, int out_size, void* d_ws, size_t ws_size,
                              hipStream_t stream) {
    const int N = in_sizes[0] / 28;       // 100000
    const int E = in_sizes[1] / 2;        // 320000
    const int G = out_size;               // 4096

    const float* x        = (const float*)d_in[0];
    const int*   ei_raw   = (const int*)d_in[1];
    const int*   b_raw    = (const int*)d_in[2];
    const float* W1_rel  = (const float*)d_in[3];
    const float* b1      = (const float*)d_in[4];
    const float* W1_root = (const float*)d_in[5];
    const float* W2_rel  = (const float*)d_in[6];
    const float* b2      = (const float*)d_in[7];
    const float* W2_root = (const float*)d_in[8];
    const float* W3_rel  = (const float*)d_in[9];
    const float* b3      = (const float*)d_in[10];
    const float* W3_root = (const float*)d_in[11];
    const float* W4_rel  = (const float*)d_in[12];
    const float* b4      = (const float*)d_in[13];
    const float* W4_root = (const float*)d_in[14];
    const float* fc1_w = (const float*)d_in[15];
    const float* fc1_b = (const float*)d_in[16];
    const float* fc2_w = (const float*)d_in[17];
    const float* fc2_b = (const float*)d_in[18];
    const float* fc3_w = (const float*)d_in[19];
    const float* fc3_b = (const float*)d_in[20];
    const float* fc4_w = (const float*)d_in[21];
    const float* fc4_b = (const float*)d_in[22];
    float* out = (float*)d_out;

    // ---- workspace layout (float units): ping-pong P0/P1 node buffers + CSR ----
    size_t fN  = (size_t)N * HID;
    size_t off_P0     = 0;
    size_t off_P1     = off_P0 + fN;
    size_t off_gpool  = off_P1 + fN;
    size_t off_t1     = off_gpool + (size_t)G * 1024;
    size_t off_t2     = off_t1 + (size_t)G * HID;
    size_t off_ei     = off_t2 + (size_t)G * HID;          // 2E ints
    size_t off_batch  = off_ei + (size_t)2 * E;            // N ints
    size_t off_starts = off_batch + (size_t)N;             // G+1 ints
    size_t off_flag   = off_starts + (size_t)(G + 1);      // 1 int
    size_t off_deg    = off_flag + 1;                      // N ints
    size_t off_cur    = off_deg + (size_t)N;               // N ints
    size_t off_rowp   = off_cur + (size_t)N;               // N+1 ints
    size_t off_bsum   = off_rowp + (size_t)(N + 1);        // 1024 ints
    size_t off_esrc   = off_bsum + 1024;                   // E ints
    size_t off_wsplit = (off_esrc + (size_t)E + 3) & ~(size_t)3;  // 16B-align
    size_t need = (off_wsplit + 393216 + 16) * 4;          // ~230 MB

    if (ws_size < need) {
        fprintf(stderr, "[kernel_launch] ws too small: ws=%zu need=%zu\n", ws_size, need);
        marker_k<<<(G + 255) / 256, 256, 0, stream>>>(out, G, (float)(ws_size >> 20));
        return;
    }

    float* wsf   = (float*)d_ws;
    float* P0    = wsf + off_P0;
    float* P1    = wsf + off_P1;
    float* gpool = wsf + off_gpool;
    float* t1    = wsf + off_t1;
    float* t2    = wsf + off_t2;
    int* nei     = (int*)(wsf + off_ei);
    int* nbatch  = (int*)(wsf + off_batch);
    int* starts  = (int*)(wsf + off_starts);
    int* flag    = (int*)(wsf + off_flag);
    int* deg     = (int*)(wsf + off_deg);
    int* cursor  = (int*)(wsf + off_cur);
    int* row_ptr = (int*)(wsf + off_rowp);
    int* bsum    = (int*)(wsf + off_bsum);
    int* esrc    = (int*)(wsf + off_esrc);
    unsigned short* wsplit = (unsigned short*)(wsf + off_wsplit);

    // ---- normalize index dtype (int64 vs int32) on-device ----
    hipMemsetAsync(flag, 0, sizeof(int), stream);
    detect64_k<<<1024, 256, 0, stream>>>((const unsigned*)ei_raw, E,
                                         (const unsigned*)b_raw, N / 2, flag);
    norm_idx_k<<<1024, 256, 0, stream>>>(ei_raw, nei, 2 * E, flag);
    norm_idx_k<<<512, 256, 0, stream>>>(b_raw, nbatch, N, flag);

    pool_bounds_k<<<(G + 1 + 255) / 256, 256, 0, stream>>>(nbatch, N, G, starts);

    // ---- build CSR by destination ----
    hipMemsetAsync(deg, 0, 2 * (size_t)N * sizeof(int), stream);
    deg_count_k<<<(E + 255) / 256, 256, 0, stream>>>(nei, E, N, deg);
    int nb = (N + 1 + SCAN_BLK - 1) / SCAN_BLK;
    if (nb <= 1024) {
        scan_a_k<<<nb, SCAN_BLK, 0, stream>>>(deg, bsum, N);
        scan_b_k<<<1, 1024, 0, stream>>>(bsum, nb);
        scan_c_k<<<nb, SCAN_BLK, 0, stream>>>(deg, bsum, row_ptr, N);
    } else {
        scan_rowptr_k<<<1, 1024, 0, stream>>>(deg, row_ptr, N);
    }
    fill_csr_k<<<(E + 255) / 256, 256, 0, stream>>>(nei, E, N, row_ptr, cursor, esrc);

    // ---- pre-split GraphConv weights (chunk-major, swizzled layout) ----
    wsplit6_k<<<dim3((65536 + 255) / 256, 6), 256, 0, stream>>>(
        W2_rel, W2_root, W3_rel, W3_root, W4_rel, W4_root, wsplit, 65536);

    int nstrips = (N + 63) / 64;

    // ---- layer 1: gather 28-wide into P1 prefix (scratch), fused GEMM -> P0 ----
    gather28_k<<<((size_t)N * 32 + 255) / 256, 256, 0, stream>>>(x, row_ptr, esrc, P1, N);
    l1_fused_k<<<nstrips, 256, 0, stream>>>(x, P1, W1_rel, W1_root, b1, P0, N);
    pool_slice_k<<<G, 256, 0, stream>>>(P0, starts, gpool + 0, N);

    // ---- layers 2..4: fused gather+GEMM, ping-pong P0 <-> P1; pool ----
    const float* bb[3] = {b2, b3, b4};
    float* bufs[2] = {P0, P1};
    for (int l = 0; l < 3; l++) {
        float* Pin  = bufs[l & 1];
        float* Pout = bufs[(l + 1) & 1];
        gemm_fused_k<<<nstrips, 256, 0, stream>>>(
            row_ptr, esrc, Pin, wsplit + (size_t)(2 * l) * 131072,
            Pout, wsplit + (size_t)(2 * l + 1) * 131072, bb[l], N);
        pool_slice_k<<<G, 256, 0, stream>>>(Pout, starts, gpool + 256 * (l + 1), N);
    }

    // ---- MLP head ----
    dim3 gdimG(G / BM, HID / BN);
    gemm_dual_k<<<gdimG, 256, 0, stream>>>(gpool, 1024, fc1_w, nullptr, 0, nullptr,
                                           fc1_b, t1, HID, G, 1024, 0, 1);
    gemm_dual_k<<<gdimG, 256, 0, stream>>>(t1, HID, fc2_w, nullptr, 0, nullptr,
                                           fc2_b, t2, HID, G, HID, 0, 1);
    gemm_dual_k<<<gdimG, 256, 0, stream>>>(t2, HID, fc3_w, nullptr, 0, nullptr,
                                           fc3_b, t1, HID, G, HID, 0, 1);
    fc4_k<<<(G * 64 + 255) / 256, 256, 0, stream>>>(t1, fc4_w, fc4_b, out, G);
}

// Round 18
// 963.911 us; speedup vs baseline: 1.0929x; 1.0929x over previous
//
#include <hip/hip_runtime.h>
#include <hip/hip_bf16.h>
#include <cstdio>

#define HID 256

using short8  = __attribute__((ext_vector_type(8))) short;
using floatx4 = __attribute__((ext_vector_type(4))) float;

typedef const unsigned int __attribute__((address_space(1)))* as1_cuintp;
typedef unsigned int __attribute__((address_space(3)))* as3_uintp;

__device__ inline unsigned short bf16_rn(float x) {
    unsigned u = __float_as_uint(x);
    return (unsigned short)((u + 0x7FFFu + ((u >> 16) & 1u)) >> 16);
}
__device__ inline float bf2f(unsigned short u) {
    return __uint_as_float(((unsigned)u) << 16);
}

// ---------------- diagnostic marker (ws too small) ----------------
__global__ void marker_k(float* __restrict__ out, int n, float v) {
    int i = blockIdx.x * blockDim.x + threadIdx.x;
    if (i < n) out[i] = v;
}

// ---------------- int64-vs-int32 detection ----------------
__global__ void detect64_k(const unsigned* __restrict__ eiw, int E,
                           const unsigned* __restrict__ bw, int Nh,
                           int* __restrict__ any_nonzero) {
    int total = E + Nh;
    unsigned loc = 0;
    for (int i = blockIdx.x * blockDim.x + threadIdx.x; i < total;
         i += gridDim.x * blockDim.x) {
        loc |= (i < E) ? eiw[2 * i + 1] : bw[2 * (i - E) + 1];
    }
    if (loc) atomicOr(any_nonzero, 1);
}

__global__ void norm_idx_k(const int* __restrict__ src, int* __restrict__ dst,
                           int n, const int* __restrict__ any_nonzero) {
    int is64 = (any_nonzero[0] == 0);
    for (int i = blockIdx.x * blockDim.x + threadIdx.x; i < n;
         i += gridDim.x * blockDim.x) {
        dst[i] = is64 ? src[2 * i] : src[i];
    }
}

// ---------------- graph boundaries (batch is sorted) ----------------
__global__ void pool_bounds_k(const int* __restrict__ batch, int N, int G,
                              int* __restrict__ starts) {
    int g = blockIdx.x * blockDim.x + threadIdx.x;
    if (g > G) return;
    int lo = 0, hi = N;
    while (lo < hi) {
        int mid = (lo + hi) >> 1;
        if (batch[mid] < g) lo = mid + 1; else hi = mid;
    }
    starts[g] = lo;
}

// ---------------- CSR build ----------------
__global__ void deg_count_k(const int* __restrict__ ei, int E, int N,
                            int* __restrict__ deg) {
    int e = blockIdx.x * blockDim.x + threadIdx.x;
    if (e >= E) return;
    int s = ei[e];
    int d = ei[E + e];
    if ((unsigned)s >= (unsigned)N || (unsigned)d >= (unsigned)N) return;
    atomicAdd(&deg[d], 1);
}

// ---- two-level grid-wide exclusive scan ----
#define SCAN_BLK 256

__global__ __launch_bounds__(SCAN_BLK) void scan_a_k(const int* __restrict__ deg,
                                                     int* __restrict__ bsum, int N) {
    __shared__ int red[SCAN_BLK];
    int i = blockIdx.x * SCAN_BLK + threadIdx.x;
    int v = (i < N) ? deg[i] : 0;
    red[threadIdx.x] = v;
    __syncthreads();
#pragma unroll
    for (int off = SCAN_BLK / 2; off > 0; off >>= 1) {
        if (threadIdx.x < off) red[threadIdx.x] += red[threadIdx.x + off];
        __syncthreads();
    }
    if (threadIdx.x == 0) bsum[blockIdx.x] = red[0];
}

__global__ __launch_bounds__(1024) void scan_b_k(int* __restrict__ bsum, int nb) {
    __shared__ int tsum[1024];
    int t = threadIdx.x;
    int v = (t < nb) ? bsum[t] : 0;
    tsum[t] = v;
    __syncthreads();
    for (int off = 1; off < 1024; off <<= 1) {
        int u = (t >= off) ? tsum[t - off] : 0;
        __syncthreads();
        tsum[t] += u;
        __syncthreads();
    }
    if (t < nb) bsum[t] = tsum[t] - v;
}

__global__ __launch_bounds__(SCAN_BLK) void scan_c_k(const int* __restrict__ deg,
                                                     const int* __restrict__ bsum,
                                                     int* __restrict__ row_ptr, int N) {
    __shared__ int tsum[SCAN_BLK];
    int t = threadIdx.x;
    int i = blockIdx.x * SCAN_BLK + t;
    int v = (i < N) ? deg[i] : 0;
    tsum[t] = v;
    __syncthreads();
    for (int off = 1; off < SCAN_BLK; off <<= 1) {
        int u = (t >= off) ? tsum[t - off] : 0;
        __syncthreads();
        tsum[t] += u;
        __syncthreads();
    }
    if (i <= N) row_ptr[i] = tsum[t] - v + bsum[blockIdx.x];
}

__global__ __launch_bounds__(1024) void scan_rowptr_k(const int* __restrict__ deg,
                                                      int* __restrict__ row_ptr, int N) {
    __shared__ int tsum[1024];
    int t = threadIdx.x;
    int chunk = (N + 1023) / 1024;
    int lo = t * chunk;
    int hi = min(lo + chunk, N);
    int s = 0;
    for (int i = lo; i < hi; i++) s += deg[i];
    tsum[t] = s;
    __syncthreads();
    for (int off = 1; off < 1024; off <<= 1) {
        int v = (t >= off) ? tsum[t - off] : 0;
        __syncthreads();
        tsum[t] += v;
        __syncthreads();
    }
    int run = (t == 0) ? 0 : tsum[t - 1];
    for (int i = lo; i < hi; i++) { row_ptr[i] = run; run += deg[i]; }
    if (hi >= N && lo <= N) row_ptr[N] = run;
}

__global__ void fill_csr_k(const int* __restrict__ ei, int E, int N,
                           const int* __restrict__ row_ptr, int* __restrict__ cursor,
                           int* __restrict__ esrc) {
    int e = blockIdx.x * blockDim.x + threadIdx.x;
    if (e >= E) return;
    int s = ei[e];
    int d = ei[E + e];
    if ((unsigned)s >= (unsigned)N || (unsigned)d >= (unsigned)N) return;
    int pos = atomicAdd(&cursor[d], 1);
    esrc[row_ptr[d] + pos] = s;
}

// ---------------- gather aggregation, 28-wide (layer 1) ----------------
__global__ void gather28_k(const float* __restrict__ x, const int* __restrict__ row_ptr,
                           const int* __restrict__ esrc, float* __restrict__ Q28, int N) {
    int gid = blockIdx.x * blockDim.x + threadIdx.x;
    int node = gid >> 5;
    if (node >= N) return;
    int lane = gid & 31;
    if (lane >= 28) return;
    int s = row_ptr[node], e = row_ptr[node + 1];
    float acc = 0.f;
    for (int i = s; i < e; i++) {
        int src = esrc[i];
        acc += x[(size_t)src * 28 + lane];
    }
    Q28[(size_t)node * 28 + lane] = acc;
}

// ---------------- gather aggregation, 256-wide (plain fp32) ----------------
__global__ void gather256_k(const float* __restrict__ P, const int* __restrict__ row_ptr,
                            const int* __restrict__ esrc, float* __restrict__ Q, int N) {
    int gid = blockIdx.x * blockDim.x + threadIdx.x;
    int node = gid >> 6;
    if (node >= N) return;
    int lane = gid & 63;
    int s = row_ptr[node], e = row_ptr[node + 1];
    float4 acc = make_float4(0.f, 0.f, 0.f, 0.f);
    for (int i = s; i < e; i++) {
        int src = esrc[i];
        float4 v = *(const float4*)(P + (size_t)src * HID + lane * 4);
        acc.x += v.x; acc.y += v.y; acc.z += v.z; acc.w += v.w;
    }
    *(float4*)(Q + (size_t)node * HID + lane * 4) = acc;
}

// ---------------- layer 1 fused: P = relu(agg28@Wrel.T + x@Wroot.T + b) ----------------
__global__ __launch_bounds__(256) void l1_fused_k(
    const float* __restrict__ x, const float* __restrict__ agg,
    const float* __restrict__ Wrel, const float* __restrict__ Wroot,
    const float* __restrict__ bias, float* __restrict__ out, int M) {
    __shared__ float As[64][28];
    __shared__ float Xs[64][28];
    int t = threadIdx.x;
    int n0 = blockIdx.x * 64;
    float wrel[28], wroot[28];
#pragma unroll
    for (int k = 0; k < 28; k++) {
        wrel[k]  = Wrel[t * 28 + k];
        wroot[k] = Wroot[t * 28 + k];
    }
    float b = bias[t];
    for (int idx = t; idx < 64 * 28; idx += 256) {
        int r = idx / 28;
        int c = idx - r * 28;
        int gr = n0 + r;
        As[r][c] = (gr < M) ? agg[(size_t)gr * 28 + c] : 0.f;
        Xs[r][c] = (gr < M) ? x[(size_t)gr * 28 + c] : 0.f;
    }
    __syncthreads();
    int nmax = min(64, M - n0);
    for (int n = 0; n < nmax; n++) {
        float acc = b;
#pragma unroll
        for (int k4 = 0; k4 < 28; k4 += 4) {
            float4 a  = *(const float4*)&As[n][k4];
            float4 xx = *(const float4*)&Xs[n][k4];
            acc += a.x * wrel[k4] + a.y * wrel[k4 + 1] + a.z * wrel[k4 + 2] + a.w * wrel[k4 + 3];
            acc += xx.x * wroot[k4] + xx.y * wroot[k4 + 1] + xx.z * wroot[k4 + 2] + xx.w * wroot[k4 + 3];
        }
        out[(size_t)(n0 + n) * HID + t] = fmaxf(acc, 0.f);
    }
}

// ---------------- weight split: chunk-major, global-load-lds-ready layout ----------------
// Per matrix (131072 ushorts): [ch 0..7][plane 0..1][col 0..255][gp 0..3][e 0..7]
// gp = sg ^ ((col>>1)&3). Staging copies one 16KB plane linearly; reads XOR.
__global__ void wsplit6_k(const float* W0, const float* W1, const float* W2,
                          const float* W3, const float* W4, const float* W5,
                          unsigned short* __restrict__ out_hl, int n) {
    int i = blockIdx.x * blockDim.x + threadIdx.x;
    if (i >= n) return;
    const float* W = (blockIdx.y == 0) ? W0 : (blockIdx.y == 1) ? W1 :
                     (blockIdx.y == 2) ? W2 : (blockIdx.y == 3) ? W3 :
                     (blockIdx.y == 4) ? W4 : W5;
    unsigned short* o = out_hl + (size_t)blockIdx.y * 131072;
    float a = W[i];
    unsigned short h = bf16_rn(a);
    unsigned short lo = bf16_rn(a - bf2f(h));
    int col = i >> 8;            // out-feature row of W
    int k   = i & 255;
    int ch  = k >> 5;
    int sg  = (k >> 3) & 3;
    int e   = k & 7;
    int gp  = sg ^ ((col >> 1) & 3);
    size_t base = (size_t)ch * 16384 + (size_t)col * 32 + gp * 8 + e;
    o[base] = h;                 // plane 0 (hi)
    o[base + 8192] = lo;         // plane 1 (lo)
}

// ---------------- MFMA strip GEMM: single-plane W LDS, wave-private plane swap ----------------
// P[strip] = relu(Q@Wr.T + P@Wo.T + bias), 64-row strip, 256 thr, 4 waves;
// wave w owns cols [w*64, w*64+64). W slice is wave-private: stage hi plane,
// consume to regs, overwrite with lo plane using wave-local waitcnts only.
// LDS 26.6KB; measured 126us, VGPR 80 (round 16).
#define LSTR 40

__global__ __launch_bounds__(256) void gemm_strip_mfma_k(
    const float* __restrict__ Q, const unsigned short* __restrict__ Wr_hl,
    float* __restrict__ P, const unsigned short* __restrict__ Wo_hl,
    const float* __restrict__ bias, int M) {
    __shared__ __attribute__((aligned(16))) unsigned short Ah[64 * LSTR];  // 5 KB
    __shared__ __attribute__((aligned(16))) unsigned short Al[64 * LSTR];  // 5 KB
    __shared__ __attribute__((aligned(16))) unsigned short Wbuf[8192];     // 16 KB (one plane)
    int t = threadIdx.x;
    int brow = blockIdx.x * 64;
    int w = t >> 6;
    int l = t & 63;

    floatx4 acc[4][4];
#pragma unroll
    for (int i = 0; i < 4; i++)
#pragma unroll
        for (int j = 0; j < 4; j++) acc[i][j] = (floatx4){0.f, 0.f, 0.f, 0.f};

    int srow = t >> 2;       // 0..63
    int sg   = t & 3;        // k-granule of 8

    for (int ch = 0; ch < 16; ch++) {
        int phase2 = (ch >= 8);
        const float* A = phase2 ? P : Q;
        const unsigned short* Whl = phase2 ? Wo_hl : Wr_hl;
        int kbase = (ch & 7) * 32;

        // ---- issue Wh (plane 0), own wave slice: 4 x 1KB via global_load_lds ----
        {
            const char* wg = (const char*)(Whl + (size_t)(ch & 7) * 16384) + w * 4096;
            char* ld = (char*)Wbuf + w * 4096;
#pragma unroll
            for (int i = 0; i < 4; i++) {
                __builtin_amdgcn_global_load_lds(
                    (as1_cuintp)(const void*)(wg + i * 1024 + l * 16),
                    (as3_uintp)(void*)(ld + i * 1024),
                    16, 0, 0);
            }
        }
        // ---- stage A: 64 rows x 32 k fp32 -> hi/lo bf16 (VGPR-lean) ----
        {
            int gr = brow + srow;
            float v[8];
            if (gr < M) {
                float4 u0 = *(const float4*)(A + (size_t)gr * HID + kbase + sg * 8);
                float4 u1 = *(const float4*)(A + (size_t)gr * HID + kbase + sg * 8 + 4);
                v[0] = u0.x; v[1] = u0.y; v[2] = u0.z; v[3] = u0.w;
                v[4] = u1.x; v[5] = u1.y; v[6] = u1.z; v[7] = u1.w;
            } else {
#pragma unroll
                for (int j = 0; j < 8; j++) v[j] = 0.f;
            }
            union { unsigned short us[8]; short8 v8; } hh, ll;
#pragma unroll
            for (int j = 0; j < 8; j++) {
                unsigned short h = bf16_rn(v[j]);
                float hf = __uint_as_float(((unsigned)h) << 16);
                hh.us[j] = h;
                ll.us[j] = bf16_rn(v[j] - hf);
            }
            int base = srow * LSTR + sg * 8;
            *(short8*)(Ah + base) = hh.v8;
            *(short8*)(Al + base) = ll.v8;
        }
        __syncthreads();   // A staged + (implicit vmcnt0) Wh landed

        // ---- fragments ----
        int frow = l & 15;
        int fg   = l >> 4;
        short8 ahf[4], alf[4], wf[4];
#pragma unroll
        for (int rt = 0; rt < 4; rt++) {
            int base = (rt * 16 + frow) * LSTR + fg * 8;
            ahf[rt] = *(short8*)(Ah + base);
            alf[rt] = *(short8*)(Al + base);
        }
#pragma unroll
        for (int ct = 0; ct < 4; ct++) {
            int col = w * 64 + ct * 16 + frow;
            int gp = fg ^ ((col >> 1) & 3);
            wf[ct] = *(short8*)(Wbuf + col * 32 + gp * 8);
        }
        // all our LDS reads (incl. wf) must complete before overwriting own W slice
        asm volatile("s_waitcnt lgkmcnt(0)" ::: "memory");
        __builtin_amdgcn_sched_barrier(0);
        // ---- issue Wl (plane 1) into the same wave-private slice ----
        {
            const char* wg = (const char*)(Whl + (size_t)(ch & 7) * 16384 + 8192) + w * 4096;
            char* ld = (char*)Wbuf + w * 4096;
#pragma unroll
            for (int i = 0; i < 4; i++) {
                __builtin_amdgcn_global_load_lds(
                    (as1_cuintp)(const void*)(wg + i * 1024 + l * 16),
                    (as3_uintp)(void*)(ld + i * 1024),
                    16, 0, 0);
            }
        }
        // ---- 32 MFMA with Wh (hides Wl L2 latency): Ah*Wh + Al*Wh ----
#pragma unroll
        for (int rt = 0; rt < 4; rt++)
#pragma unroll
            for (int ct = 0; ct < 4; ct++) {
                acc[rt][ct] = __builtin_amdgcn_mfma_f32_16x16x32_bf16(
                    ahf[rt], wf[ct], acc[rt][ct], 0, 0, 0);
                acc[rt][ct] = __builtin_amdgcn_mfma_f32_16x16x32_bf16(
                    alf[rt], wf[ct], acc[rt][ct], 0, 0, 0);
            }
        // ---- wave-local wait for Wl, then 16 MFMA: Ah*Wl ----
        asm volatile("s_waitcnt vmcnt(0)" ::: "memory");
        __builtin_amdgcn_sched_barrier(0);
#pragma unroll
        for (int ct = 0; ct < 4; ct++) {
            int col = w * 64 + ct * 16 + frow;
            int gp = fg ^ ((col >> 1) & 3);
            wf[ct] = *(short8*)(Wbuf + col * 32 + gp * 8);
        }
#pragma unroll
        for (int rt = 0; rt < 4; rt++)
#pragma unroll
            for (int ct = 0; ct < 4; ct++)
                acc[rt][ct] = __builtin_amdgcn_mfma_f32_16x16x32_bf16(
                    ahf[rt], wf[ct], acc[rt][ct], 0, 0, 0);
        __syncthreads();   // before next chunk overwrites Ah/Al (and our wlf reads done)
    }

    // ---- epilogue: C/D layout col=lane&15, row=(lane>>4)*4+reg ----
#pragma unroll
    for (int ct = 0; ct < 4; ct++) {
        int gc = w * 64 + ct * 16 + (l & 15);
        float bs = bias[gc];
#pragma unroll
        for (int rt = 0; rt < 4; rt++) {
            floatx4 a = acc[rt][ct];
#pragma unroll
            for (int r = 0; r < 4; r++) {
                int gr = brow + rt * 16 + (l >> 4) * 4 + r;
                if (gr < M)
                    P[(size_t)gr * HID + gc] = fmaxf(a[r] + bs, 0.f);
            }
        }
    }
}

// ---------------- per-layer mean-pool slice ----------------
__global__ __launch_bounds__(256) void pool_slice_k(const float* __restrict__ xl,
                                                    const int* __restrict__ starts,
                                                    float* __restrict__ gslice, int N) {
    int g = blockIdx.x;
    int t = threadIdx.x;
    int s = starts[g], e = starts[g + 1];
    s = max(0, min(s, N));
    e = max(s, min(e, N));
    float a = 0.f;
    for (int n = s; n < e; n++) a += xl[(size_t)n * HID + t];
    float inv = 1.f / (float)max(e - s, 1);
    gslice[(size_t)g * 1024 + t] = a * inv;
}

// ---------------- out-of-place dual GEMM (MLP head, fp32) ----------------
#define BM 64
#define BN 64
#define BK 32
#define LP 68

__global__ __launch_bounds__(256) void gemm_dual_k(
    const float* __restrict__ A1, int lda1, const float* __restrict__ W1,
    const float* __restrict__ A2, int lda2, const float* __restrict__ W2,
    const float* __restrict__ bias, float* __restrict__ out, int ldout,
    int M, int K1, int K2, int relu) {
    __shared__ float As[BK][LP];
    __shared__ float Ws[BK][LP];
    int t = threadIdx.x;
    int brow = blockIdx.x * BM;
    int bcol = blockIdx.y * BN;
    int tx = t & 15, ty = t >> 4;
    float acc[4][4] = {{0.f}};
    int Ktot = K1 + K2;
    int srow = t >> 3;
    int sk4 = (t & 7) << 2;

    for (int kk = 0; kk < Ktot; kk += BK) {
        int phase2 = (kk >= K1);
        const float* A = phase2 ? A2 : A1;
        const float* W = phase2 ? W2 : W1;
        int lda = phase2 ? lda2 : lda1;
        int ldw = phase2 ? K2 : K1;
        int kbase = phase2 ? (kk - K1) : kk;
#pragma unroll
        for (int i = 0; i < 2; i++) {
            int r = srow + i * 32;
            int gr = brow + r;
            float4 v = make_float4(0.f, 0.f, 0.f, 0.f);
            if (gr < M) v = *(const float4*)(A + (size_t)gr * lda + kbase + sk4);
            As[sk4 + 0][r] = v.x; As[sk4 + 1][r] = v.y;
            As[sk4 + 2][r] = v.z; As[sk4 + 3][r] = v.w;
            float4 w = *(const float4*)(W + (size_t)(bcol + r) * ldw + kbase + sk4);
            Ws[sk4 + 0][r] = w.x; Ws[sk4 + 1][r] = w.y;
            Ws[sk4 + 2][r] = w.z; Ws[sk4 + 3][r] = w.w;
        }
        __syncthreads();
#pragma unroll
        for (int k = 0; k < BK; k++) {
            float4 a = *(const float4*)&As[k][ty << 2];
            float4 w = *(const float4*)&Ws[k][tx << 2];
            float av[4] = {a.x, a.y, a.z, a.w};
            float wv[4] = {w.x, w.y, w.z, w.w};
#pragma unroll
            for (int i = 0; i < 4; i++)
#pragma unroll
                for (int j = 0; j < 4; j++)
                    acc[i][j] = fmaf(av[i], wv[j], acc[i][j]);
        }
        __syncthreads();
    }
#pragma unroll
    for (int i = 0; i < 4; i++) {
        int gr = brow + (ty << 2) + i;
        if (gr >= M) continue;
#pragma unroll
        for (int j = 0; j < 4; j++) {
            int gc = bcol + (tx << 2) + j;
            float v = acc[i][j] + bias[gc];
            if (relu) v = fmaxf(v, 0.f);
            out[(size_t)gr * ldout + gc] = v;
        }
    }
}

// ---------------- fc4 ----------------
__global__ void fc4_k(const float* __restrict__ in, const float* __restrict__ w,
                      const float* __restrict__ b, float* __restrict__ out, int M) {
    int gid = blockIdx.x * blockDim.x + threadIdx.x;
    int row = gid >> 6;
    if (row >= M) return;
    int lane = gid & 63;
    float4 v  = *(const float4*)(in + (size_t)row * HID + lane * 4);
    float4 ww = *(const float4*)(w + lane * 4);
    float acc = v.x * ww.x + v.y * ww.y + v.z * ww.z + v.w * ww.w;
#pragma unroll
    for (int off = 32; off; off >>= 1) acc += __shfl_down(acc, off);
    if (lane == 0) out[row] = acc + b[0];
}

extern "C" void kernel_launch(void* const* d_in, const int* in_sizes, int n_in,
                              void* d_out, int out_size, void* d_ws, size_t ws_size,
                              hipStream_t stream) {
    const int N = in_sizes[0] / 28;       // 100000
    const int E = in_sizes[1] / 2;        // 320000
    const int G = out_size;               // 4096

    const float* x        = (const float*)d_in[0];
    const int*   ei_raw   = (const int*)d_in[1];
    const int*   b_raw    = (const int*)d_in[2];
    const float* W1_rel  = (const float*)d_in[3];
    const float* b1      = (const float*)d_in[4];
    const float* W1_root = (const float*)d_in[5];
    const float* W2_rel  = (const float*)d_in[6];
    const float* b2      = (const float*)d_in[7];
    const float* W2_root = (const float*)d_in[8];
    const float* W3_rel  = (const float*)d_in[9];
    const float* b3      = (const float*)d_in[10];
    const float* W3_root = (const float*)d_in[11];
    const float* W4_rel  = (const float*)d_in[12];
    const float* b4      = (const float*)d_in[13];
    const float* W4_root = (const float*)d_in[14];
    const float* fc1_w = (const float*)d_in[15];
    const float* fc1_b = (const float*)d_in[16];
    const float* fc2_w = (const float*)d_in[17];
    const float* fc2_b = (const float*)d_in[18];
    const float* fc3_w = (const float*)d_in[19];
    const float* fc3_b = (const float*)d_in[20];
    const float* fc4_w = (const float*)d_in[21];
    const float* fc4_b = (const float*)d_in[22];
    float* out = (float*)d_out;

    // ---- workspace layout (float units): fp32 P and Q node buffers + CSR ----
    size_t fN  = (size_t)N * HID;
    size_t off_P      = 0;
    size_t off_Q      = off_P + fN;
    size_t off_gpool  = off_Q + fN;
    size_t off_t1     = off_gpool + (size_t)G * 1024;
    size_t off_t2     = off_t1 + (size_t)G * HID;
    size_t off_ei     = off_t2 + (size_t)G * HID;          // 2E ints
    size_t off_batch  = off_ei + (size_t)2 * E;            // N ints
    size_t off_starts = off_batch + (size_t)N;             // G+1 ints
    size_t off_flag   = off_starts + (size_t)(G + 1);      // 1 int
    size_t off_deg    = off_flag + 1;                      // N ints
    size_t off_cur    = off_deg + (size_t)N;               // N ints
    size_t off_rowp   = off_cur + (size_t)N;               // N+1 ints
    size_t off_bsum   = off_rowp + (size_t)(N + 1);        // 1024 ints
    size_t off_esrc   = off_bsum + 1024;                   // E ints
    size_t off_wsplit = (off_esrc + (size_t)E + 3) & ~(size_t)3;  // 16B-align
    size_t need = (off_wsplit + 393216 + 16) * 4;          // ~230 MB

    if (ws_size < need) {
        fprintf(stderr, "[kernel_launch] ws too small: ws=%zu need=%zu\n", ws_size, need);
        marker_k<<<(G + 255) / 256, 256, 0, stream>>>(out, G, (float)(ws_size >> 20));
        return;
    }

    float* wsf   = (float*)d_ws;
    float* P     = wsf + off_P;
    float* Q     = wsf + off_Q;
    float* gpool = wsf + off_gpool;
    float* t1    = wsf + off_t1;
    float* t2    = wsf + off_t2;
    int* nei     = (int*)(wsf + off_ei);
    int* nbatch  = (int*)(wsf + off_batch);
    int* starts  = (int*)(wsf + off_starts);
    int* flag    = (int*)(wsf + off_flag);
    int* deg     = (int*)(wsf + off_deg);
    int* cursor  = (int*)(wsf + off_cur);
    int* row_ptr = (int*)(wsf + off_rowp);
    int* bsum    = (int*)(wsf + off_bsum);
    int* esrc    = (int*)(wsf + off_esrc);
    unsigned short* wsplit = (unsigned short*)(wsf + off_wsplit);

    // ---- normalize index dtype (int64 vs int32) on-device ----
    hipMemsetAsync(flag, 0, sizeof(int), stream);
    detect64_k<<<1024, 256, 0, stream>>>((const unsigned*)ei_raw, E,
                                         (const unsigned*)b_raw, N / 2, flag);
    norm_idx_k<<<1024, 256, 0, stream>>>(ei_raw, nei, 2 * E, flag);
    norm_idx_k<<<512, 256, 0, stream>>>(b_raw, nbatch, N, flag);

    pool_bounds_k<<<(G + 1 + 255) / 256, 256, 0, stream>>>(nbatch, N, G, starts);

    // ---- build CSR by destination ----
    hipMemsetAsync(deg, 0, 2 * (size_t)N * sizeof(int), stream);
    deg_count_k<<<(E + 255) / 256, 256, 0, stream>>>(nei, E, N, deg);
    int nb = (N + 1 + SCAN_BLK - 1) / SCAN_BLK;
    if (nb <= 1024) {
        scan_a_k<<<nb, SCAN_BLK, 0, stream>>>(deg, bsum, N);
        scan_b_k<<<1, 1024, 0, stream>>>(bsum, nb);
        scan_c_k<<<nb, SCAN_BLK, 0, stream>>>(deg, bsum, row_ptr, N);
    } else {
        scan_rowptr_k<<<1, 1024, 0, stream>>>(deg, row_ptr, N);
    }
    fill_csr_k<<<(E + 255) / 256, 256, 0, stream>>>(nei, E, N, row_ptr, cursor, esrc);

    // ---- pre-split GraphConv weights (chunk-major, swizzled layout) ----
    wsplit6_k<<<dim3((65536 + 255) / 256, 6), 256, 0, stream>>>(
        W2_rel, W2_root, W3_rel, W3_root, W4_rel, W4_root, wsplit, 65536);

    int nstrips = (N + 63) / 64;

    // ---- layer 1: gather 28-wide into Q prefix, fused GEMM -> P ----
    gather28_k<<<((size_t)N * 32 + 255) / 256, 256, 0, stream>>>(x, row_ptr, esrc, Q, N);
    l1_fused_k<<<nstrips, 256, 0, stream>>>(x, Q, W1_rel, W1_root, b1, P, N);
    pool_slice_k<<<G, 256, 0, stream>>>(P, starts, gpool + 0, N);

    // ---- layers 2..4: gather P->Q; MFMA strip GEMM in-place on P; pool ----
    const float* bb[3] = {b2, b3, b4};
    for (int l = 0; l < 3; l++) {
        gather256_k<<<((size_t)N * 64 + 255) / 256, 256, 0, stream>>>(P, row_ptr, esrc, Q, N);
        gemm_strip_mfma_k<<<nstrips, 256, 0, stream>>>(
            Q, wsplit + (size_t)(2 * l) * 131072,
            P, wsplit + (size_t)(2 * l + 1) * 131072, bb[l], N);
        pool_slice_k<<<G, 256, 0, stream>>>(P, starts, gpool + 256 * (l + 1), N);
    }

    // ---- MLP head ----
    dim3 gdimG(G / BM, HID / BN);
    gemm_dual_k<<<gdimG, 256, 0, stream>>>(gpool, 1024, fc1_w, nullptr, 0, nullptr,
                                           fc1_b, t1, HID, G, 1024, 0, 1);
    gemm_dual_k<<<gdimG, 256, 0, stream>>>(t1, HID, fc2_w, nullptr, 0, nullptr,
                                           fc2_b, t2, HID, G, HID, 0, 1);
    gemm_dual_k<<<gdimG, 256, 0, stream>>>(t2, HID, fc3_w, nullptr, 0, nullptr,
                                           fc3_b, t1, HID, G, HID, 0, 1);
    fc4_k<<<(G * 64 + 255) / 256, 256, 0, stream>>>(t1, fc4_w, fc4_b, out, G);
}

// Round 19
// 953.993 us; speedup vs baseline: 1.1043x; 1.0104x over previous
//
#include <hip/hip_runtime.h>
#include <hip/hip_bf16.h>
#include <cstdio>

#define HID 256

using short8  = __attribute__((ext_vector_type(8))) short;
using floatx4 = __attribute__((ext_vector_type(4))) float;

typedef const unsigned int __attribute__((address_space(1)))* as1_cuintp;
typedef unsigned int __attribute__((address_space(3)))* as3_uintp;

__device__ inline unsigned short bf16_rn(float x) {
    unsigned u = __float_as_uint(x);
    return (unsigned short)((u + 0x7FFFu + ((u >> 16) & 1u)) >> 16);
}
__device__ inline float bf2f(unsigned short u) {
    return __uint_as_float(((unsigned)u) << 16);
}

// ---------------- diagnostic marker (ws too small) ----------------
__global__ void marker_k(float* __restrict__ out, int n, float v) {
    int i = blockIdx.x * blockDim.x + threadIdx.x;
    if (i < n) out[i] = v;
}

// ---------------- int64-vs-int32 detection ----------------
__global__ void detect64_k(const unsigned* __restrict__ eiw, int E,
                           const unsigned* __restrict__ bw, int Nh,
                           int* __restrict__ any_nonzero) {
    int total = E + Nh;
    unsigned loc = 0;
    for (int i = blockIdx.x * blockDim.x + threadIdx.x; i < total;
         i += gridDim.x * blockDim.x) {
        loc |= (i < E) ? eiw[2 * i + 1] : bw[2 * (i - E) + 1];
    }
    if (loc) atomicOr(any_nonzero, 1);
}

__global__ void norm_idx_k(const int* __restrict__ src, int* __restrict__ dst,
                           int n, const int* __restrict__ any_nonzero) {
    int is64 = (any_nonzero[0] == 0);
    for (int i = blockIdx.x * blockDim.x + threadIdx.x; i < n;
         i += gridDim.x * blockDim.x) {
        dst[i] = is64 ? src[2 * i] : src[i];
    }
}

// ---------------- graph boundaries (batch is sorted) ----------------
__global__ void pool_bounds_k(const int* __restrict__ batch, int N, int G,
                              int* __restrict__ starts) {
    int g = blockIdx.x * blockDim.x + threadIdx.x;
    if (g > G) return;
    int lo = 0, hi = N;
    while (lo < hi) {
        int mid = (lo + hi) >> 1;
        if (batch[mid] < g) lo = mid + 1; else hi = mid;
    }
    starts[g] = lo;
}

// ---------------- CSR build ----------------
__global__ void deg_count_k(const int* __restrict__ ei, int E, int N,
                            int* __restrict__ deg) {
    int e = blockIdx.x * blockDim.x + threadIdx.x;
    if (e >= E) return;
    int s = ei[e];
    int d = ei[E + e];
    if ((unsigned)s >= (unsigned)N || (unsigned)d >= (unsigned)N) return;
    atomicAdd(&deg[d], 1);
}

// ---- two-level grid-wide exclusive scan ----
#define SCAN_BLK 256

__global__ __launch_bounds__(SCAN_BLK) void scan_a_k(const int* __restrict__ deg,
                                                     int* __restrict__ bsum, int N) {
    __shared__ int red[SCAN_BLK];
    int i = blockIdx.x * SCAN_BLK + threadIdx.x;
    int v = (i < N) ? deg[i] : 0;
    red[threadIdx.x] = v;
    __syncthreads();
#pragma unroll
    for (int off = SCAN_BLK / 2; off > 0; off >>= 1) {
        if (threadIdx.x < off) red[threadIdx.x] += red[threadIdx.x + off];
        __syncthreads();
    }
    if (threadIdx.x == 0) bsum[blockIdx.x] = red[0];
}

__global__ __launch_bounds__(1024) void scan_b_k(int* __restrict__ bsum, int nb) {
    __shared__ int tsum[1024];
    int t = threadIdx.x;
    int v = (t < nb) ? bsum[t] : 0;
    tsum[t] = v;
    __syncthreads();
    for (int off = 1; off < 1024; off <<= 1) {
        int u = (t >= off) ? tsum[t - off] : 0;
        __syncthreads();
        tsum[t] += u;
        __syncthreads();
    }
    if (t < nb) bsum[t] = tsum[t] - v;
}

__global__ __launch_bounds__(SCAN_BLK) void scan_c_k(const int* __restrict__ deg,
                                                     const int* __restrict__ bsum,
                                                     int* __restrict__ row_ptr, int N) {
    __shared__ int tsum[SCAN_BLK];
    int t = threadIdx.x;
    int i = blockIdx.x * SCAN_BLK + t;
    int v = (i < N) ? deg[i] : 0;
    tsum[t] = v;
    __syncthreads();
    for (int off = 1; off < SCAN_BLK; off <<= 1) {
        int u = (t >= off) ? tsum[t - off] : 0;
        __syncthreads();
        tsum[t] += u;
        __syncthreads();
    }
    if (i <= N) row_ptr[i] = tsum[t] - v + bsum[blockIdx.x];
}

__global__ __launch_bounds__(1024) void scan_rowptr_k(const int* __restrict__ deg,
                                                      int* __restrict__ row_ptr, int N) {
    __shared__ int tsum[1024];
    int t = threadIdx.x;
    int chunk = (N + 1023) / 1024;
    int lo = t * chunk;
    int hi = min(lo + chunk, N);
    int s = 0;
    for (int i = lo; i < hi; i++) s += deg[i];
    tsum[t] = s;
    __syncthreads();
    for (int off = 1; off < 1024; off <<= 1) {
        int v = (t >= off) ? tsum[t - off] : 0;
        __syncthreads();
        tsum[t] += v;
        __syncthreads();
    }
    int run = (t == 0) ? 0 : tsum[t - 1];
    for (int i = lo; i < hi; i++) { row_ptr[i] = run; run += deg[i]; }
    if (hi >= N && lo <= N) row_ptr[N] = run;
}

__global__ void fill_csr_k(const int* __restrict__ ei, int E, int N,
                           const int* __restrict__ row_ptr, int* __restrict__ cursor,
                           int* __restrict__ esrc) {
    int e = blockIdx.x * blockDim.x + threadIdx.x;
    if (e >= E) return;
    int s = ei[e];
    int d = ei[E + e];
    if ((unsigned)s >= (unsigned)N || (unsigned)d >= (unsigned)N) return;
    int pos = atomicAdd(&cursor[d], 1);
    esrc[row_ptr[d] + pos] = s;
}

// ---------------- gather aggregation, 28-wide (layer 1) ----------------
__global__ void gather28_k(const float* __restrict__ x, const int* __restrict__ row_ptr,
                           const int* __restrict__ esrc, float* __restrict__ Q28, int N) {
    int gid = blockIdx.x * blockDim.x + threadIdx.x;
    int node = gid >> 5;
    if (node >= N) return;
    int lane = gid & 31;
    if (lane >= 28) return;
    int s = row_ptr[node], e = row_ptr[node + 1];
    float acc = 0.f;
    for (int i = s; i < e; i++) {
        int src = esrc[i];
        acc += x[(size_t)src * 28 + lane];
    }
    Q28[(size_t)node * 28 + lane] = acc;
}

// ---------------- gather aggregation, 256-wide (plain fp32) ----------------
__global__ void gather256_k(const float* __restrict__ P, const int* __restrict__ row_ptr,
                            const int* __restrict__ esrc, float* __restrict__ Q, int N) {
    int gid = blockIdx.x * blockDim.x + threadIdx.x;
    int node = gid >> 6;
    if (node >= N) return;
    int lane = gid & 63;
    int s = row_ptr[node], e = row_ptr[node + 1];
    float4 acc = make_float4(0.f, 0.f, 0.f, 0.f);
    for (int i = s; i < e; i++) {
        int src = esrc[i];
        float4 v = *(const float4*)(P + (size_t)src * HID + lane * 4);
        acc.x += v.x; acc.y += v.y; acc.z += v.z; acc.w += v.w;
    }
    *(float4*)(Q + (size_t)node * HID + lane * 4) = acc;
}

// ---------------- layer 1 fused: P = relu(agg28@Wrel.T + x@Wroot.T + b) ----------------
__global__ __launch_bounds__(256) void l1_fused_k(
    const float* __restrict__ x, const float* __restrict__ agg,
    const float* __restrict__ Wrel, const float* __restrict__ Wroot,
    const float* __restrict__ bias, float* __restrict__ out, int M) {
    __shared__ float As[64][28];
    __shared__ float Xs[64][28];
    int t = threadIdx.x;
    int n0 = blockIdx.x * 64;
    float wrel[28], wroot[28];
#pragma unroll
    for (int k = 0; k < 28; k++) {
        wrel[k]  = Wrel[t * 28 + k];
        wroot[k] = Wroot[t * 28 + k];
    }
    float b = bias[t];
    for (int idx = t; idx < 64 * 28; idx += 256) {
        int r = idx / 28;
        int c = idx - r * 28;
        int gr = n0 + r;
        As[r][c] = (gr < M) ? agg[(size_t)gr * 28 + c] : 0.f;
        Xs[r][c] = (gr < M) ? x[(size_t)gr * 28 + c] : 0.f;
    }
    __syncthreads();
    int nmax = min(64, M - n0);
    for (int n = 0; n < nmax; n++) {
        float acc = b;
#pragma unroll
        for (int k4 = 0; k4 < 28; k4 += 4) {
            float4 a  = *(const float4*)&As[n][k4];
            float4 xx = *(const float4*)&Xs[n][k4];
            acc += a.x * wrel[k4] + a.y * wrel[k4 + 1] + a.z * wrel[k4 + 2] + a.w * wrel[k4 + 3];
            acc += xx.x * wroot[k4] + xx.y * wroot[k4 + 1] + xx.z * wroot[k4 + 2] + xx.w * wroot[k4 + 3];
        }
        out[(size_t)(n0 + n) * HID + t] = fmaxf(acc, 0.f);
    }
}

// ---------------- weight split: chunk-major, global-load-lds-ready layout ----------------
__global__ void wsplit6_k(const float* W0, const float* W1, const float* W2,
                          const float* W3, const float* W4, const float* W5,
                          unsigned short* __restrict__ out_hl, int n) {
    int i = blockIdx.x * blockDim.x + threadIdx.x;
    if (i >= n) return;
    const float* W = (blockIdx.y == 0) ? W0 : (blockIdx.y == 1) ? W1 :
                     (blockIdx.y == 2) ? W2 : (blockIdx.y == 3) ? W3 :
                     (blockIdx.y == 4) ? W4 : W5;
    unsigned short* o = out_hl + (size_t)blockIdx.y * 131072;
    float a = W[i];
    unsigned short h = bf16_rn(a);
    unsigned short lo = bf16_rn(a - bf2f(h));
    int col = i >> 8;
    int k   = i & 255;
    int ch  = k >> 5;
    int sg  = (k >> 3) & 3;
    int e   = k & 7;
    int gp  = sg ^ ((col >> 1) & 3);
    size_t base = (size_t)ch * 16384 + (size_t)col * 32 + gp * 8 + e;
    o[base] = h;
    o[base + 8192] = lo;
}

// ---------------- MFMA strip GEMM (round-16 structure + T5 setprio) ----------------
#define LSTR 40

__global__ __launch_bounds__(256) void gemm_strip_mfma_k(
    const float* __restrict__ Q, const unsigned short* __restrict__ Wr_hl,
    float* __restrict__ P, const unsigned short* __restrict__ Wo_hl,
    const float* __restrict__ bias, int M) {
    __shared__ __attribute__((aligned(16))) unsigned short Ah[64 * LSTR];
    __shared__ __attribute__((aligned(16))) unsigned short Al[64 * LSTR];
    __shared__ __attribute__((aligned(16))) unsigned short Wbuf[8192];
    int t = threadIdx.x;
    int brow = blockIdx.x * 64;
    int w = t >> 6;
    int l = t & 63;

    floatx4 acc[4][4];
#pragma unroll
    for (int i = 0; i < 4; i++)
#pragma unroll
        for (int j = 0; j < 4; j++) acc[i][j] = (floatx4){0.f, 0.f, 0.f, 0.f};

    int srow = t >> 2;
    int sg   = t & 3;

    for (int ch = 0; ch < 16; ch++) {
        int phase2 = (ch >= 8);
        const float* A = phase2 ? P : Q;
        const unsigned short* Whl = phase2 ? Wo_hl : Wr_hl;
        int kbase = (ch & 7) * 32;

        // ---- issue Wh (plane 0), own wave slice ----
        {
            const char* wg = (const char*)(Whl + (size_t)(ch & 7) * 16384) + w * 4096;
            char* ld = (char*)Wbuf + w * 4096;
#pragma unroll
            for (int i = 0; i < 4; i++) {
                __builtin_amdgcn_global_load_lds(
                    (as1_cuintp)(const void*)(wg + i * 1024 + l * 16),
                    (as3_uintp)(void*)(ld + i * 1024),
                    16, 0, 0);
            }
        }
        // ---- stage A: fp32 -> hi/lo bf16 ----
        {
            int gr = brow + srow;
            float v[8];
            if (gr < M) {
                float4 u0 = *(const float4*)(A + (size_t)gr * HID + kbase + sg * 8);
                float4 u1 = *(const float4*)(A + (size_t)gr * HID + kbase + sg * 8 + 4);
                v[0] = u0.x; v[1] = u0.y; v[2] = u0.z; v[3] = u0.w;
                v[4] = u1.x; v[5] = u1.y; v[6] = u1.z; v[7] = u1.w;
            } else {
#pragma unroll
                for (int j = 0; j < 8; j++) v[j] = 0.f;
            }
            union { unsigned short us[8]; short8 v8; } hh, ll;
#pragma unroll
            for (int j = 0; j < 8; j++) {
                unsigned short h = bf16_rn(v[j]);
                float hf = __uint_as_float(((unsigned)h) << 16);
                hh.us[j] = h;
                ll.us[j] = bf16_rn(v[j] - hf);
            }
            int base = srow * LSTR + sg * 8;
            *(short8*)(Ah + base) = hh.v8;
            *(short8*)(Al + base) = ll.v8;
        }
        __syncthreads();

        // ---- fragments ----
        int frow = l & 15;
        int fg   = l >> 4;
        short8 ahf[4], alf[4], wf[4];
#pragma unroll
        for (int rt = 0; rt < 4; rt++) {
            int base = (rt * 16 + frow) * LSTR + fg * 8;
            ahf[rt] = *(short8*)(Ah + base);
            alf[rt] = *(short8*)(Al + base);
        }
#pragma unroll
        for (int ct = 0; ct < 4; ct++) {
            int col = w * 64 + ct * 16 + frow;
            int gp = fg ^ ((col >> 1) & 3);
            wf[ct] = *(short8*)(Wbuf + col * 32 + gp * 8);
        }
        asm volatile("s_waitcnt lgkmcnt(0)" ::: "memory");
        __builtin_amdgcn_sched_barrier(0);
        // ---- issue Wl (plane 1) into the same wave-private slice ----
        {
            const char* wg = (const char*)(Whl + (size_t)(ch & 7) * 16384 + 8192) + w * 4096;
            char* ld = (char*)Wbuf + w * 4096;
#pragma unroll
            for (int i = 0; i < 4; i++) {
                __builtin_amdgcn_global_load_lds(
                    (as1_cuintp)(const void*)(wg + i * 1024 + l * 16),
                    (as3_uintp)(void*)(ld + i * 1024),
                    16, 0, 0);
            }
        }
        // ---- 32 MFMA with Wh (T5: prioritize MFMA-issuing waves) ----
        __builtin_amdgcn_s_setprio(1);
#pragma unroll
        for (int rt = 0; rt < 4; rt++)
#pragma unroll
            for (int ct = 0; ct < 4; ct++) {
                acc[rt][ct] = __builtin_amdgcn_mfma_f32_16x16x32_bf16(
                    ahf[rt], wf[ct], acc[rt][ct], 0, 0, 0);
                acc[rt][ct] = __builtin_amdgcn_mfma_f32_16x16x32_bf16(
                    alf[rt], wf[ct], acc[rt][ct], 0, 0, 0);
            }
        __builtin_amdgcn_s_setprio(0);
        // ---- wave-local wait for Wl, then 16 MFMA: Ah*Wl ----
        asm volatile("s_waitcnt vmcnt(0)" ::: "memory");
        __builtin_amdgcn_sched_barrier(0);
#pragma unroll
        for (int ct = 0; ct < 4; ct++) {
            int col = w * 64 + ct * 16 + frow;
            int gp = fg ^ ((col >> 1) & 3);
            wf[ct] = *(short8*)(Wbuf + col * 32 + gp * 8);
        }
        __builtin_amdgcn_s_setprio(1);
#pragma unroll
        for (int rt = 0; rt < 4; rt++)
#pragma unroll
            for (int ct = 0; ct < 4; ct++)
                acc[rt][ct] = __builtin_amdgcn_mfma_f32_16x16x32_bf16(
                    ahf[rt], wf[ct], acc[rt][ct], 0, 0, 0);
        __builtin_amdgcn_s_setprio(0);
        __syncthreads();
    }

    // ---- epilogue ----
#pragma unroll
    for (int ct = 0; ct < 4; ct++) {
        int gc = w * 64 + ct * 16 + (l & 15);
        float bs = bias[gc];
#pragma unroll
        for (int rt = 0; rt < 4; rt++) {
            floatx4 a = acc[rt][ct];
#pragma unroll
            for (int r = 0; r < 4; r++) {
                int gr = brow + rt * 16 + (l >> 4) * 4 + r;
                if (gr < M)
                    P[(size_t)gr * HID + gc] = fmaxf(a[r] + bs, 0.f);
            }
        }
    }
}

// ---------------- per-layer mean-pool slice ----------------
__global__ __launch_bounds__(256) void pool_slice_k(const float* __restrict__ xl,
                                                    const int* __restrict__ starts,
                                                    float* __restrict__ gslice, int N) {
    int g = blockIdx.x;
    int t = threadIdx.x;
    int s = starts[g], e = starts[g + 1];
    s = max(0, min(s, N));
    e = max(s, min(e, N));
    float a = 0.f;
    for (int n = s; n < e; n++) a += xl[(size_t)n * HID + t];
    float inv = 1.f / (float)max(e - s, 1);
    gslice[(size_t)g * 1024 + t] = a * inv;
}

// ---------------- out-of-place dual GEMM (MLP head, fp32) ----------------
#define BM 64
#define BN 64
#define BK 32
#define LP 68

__global__ __launch_bounds__(256) void gemm_dual_k(
    const float* __restrict__ A1, int lda1, const float* __restrict__ W1,
    const float* __restrict__ A2, int lda2, const float* __restrict__ W2,
    const float* __restrict__ bias, float* __restrict__ out, int ldout,
    int M, int K1, int K2, int relu) {
    __shared__ float As[BK][LP];
    __shared__ float Ws[BK][LP];
    int t = threadIdx.x;
    int brow = blockIdx.x * BM;
    int bcol = blockIdx.y * BN;
    int tx = t & 15, ty = t >> 4;
    float acc[4][4] = {{0.f}};
    int Ktot = K1 + K2;
    int srow = t >> 3;
    int sk4 = (t & 7) << 2;

    for (int kk = 0; kk < Ktot; kk += BK) {
        int phase2 = (kk >= K1);
        const float* A = phase2 ? A2 : A1;
        const float* W = phase2 ? W2 : W1;
        int lda = phase2 ? lda2 : lda1;
        int ldw = phase2 ? K2 : K1;
        int kbase = phase2 ? (kk - K1) : kk;
#pragma unroll
        for (int i = 0; i < 2; i++) {
            int r = srow + i * 32;
            int gr = brow + r;
            float4 v = make_float4(0.f, 0.f, 0.f, 0.f);
            if (gr < M) v = *(const float4*)(A + (size_t)gr * lda + kbase + sk4);
            As[sk4 + 0][r] = v.x; As[sk4 + 1][r] = v.y;
            As[sk4 + 2][r] = v.z; As[sk4 + 3][r] = v.w;
            float4 w = *(const float4*)(W + (size_t)(bcol + r) * ldw + kbase + sk4);
            Ws[sk4 + 0][r] = w.x; Ws[sk4 + 1][r] = w.y;
            Ws[sk4 + 2][r] = w.z; Ws[sk4 + 3][r] = w.w;
        }
        __syncthreads();
#pragma unroll
        for (int k = 0; k < BK; k++) {
            float4 a = *(const float4*)&As[k][ty << 2];
            float4 w = *(const float4*)&Ws[k][tx << 2];
            float av[4] = {a.x, a.y, a.z, a.w};
            float wv[4] = {w.x, w.y, w.z, w.w};
#pragma unroll
            for (int i = 0; i < 4; i++)
#pragma unroll
                for (int j = 0; j < 4; j++)
                    acc[i][j] = fmaf(av[i], wv[j], acc[i][j]);
        }
        __syncthreads();
    }
#pragma unroll
    for (int i = 0; i < 4; i++) {
        int gr = brow + (ty << 2) + i;
        if (gr >= M) continue;
#pragma unroll
        for (int j = 0; j < 4; j++) {
            int gc = bcol + (tx << 2) + j;
            float v = acc[i][j] + bias[gc];
            if (relu) v = fmaxf(v, 0.f);
            out[(size_t)gr * ldout + gc] = v;
        }
    }
}

// ---------------- fc4 ----------------
__global__ void fc4_k(const float* __restrict__ in, const float* __restrict__ w,
                      const float* __restrict__ b, float* __restrict__ out, int M) {
    int gid = blockIdx.x * blockDim.x + threadIdx.x;
    int row = gid >> 6;
    if (row >= M) return;
    int lane = gid & 63;
    float4 v  = *(const float4*)(in + (size_t)row * HID + lane * 4);
    float4 ww = *(const float4*)(w + lane * 4);
    float acc = v.x * ww.x + v.y * ww.y + v.z * ww.z + v.w * ww.w;
#pragma unroll
    for (int off = 32; off; off >>= 1) acc += __shfl_down(acc, off);
    if (lane == 0) out[row] = acc + b[0];
}

extern "C" void kernel_launch(void* const* d_in, const int* in_sizes, int n_in,
                              void* d_out, int out_size, void* d_ws, size_t ws_size,
                              hipStream_t stream) {
    const int N = in_sizes[0] / 28;       // 100000
    const int E = in_sizes[1] / 2;        // 320000
    const int G = out_size;               // 4096

    const float* x        = (const float*)d_in[0];
    const int*   ei_raw   = (const int*)d_in[1];
    const int*   b_raw    = (const int*)d_in[2];
    const float* W1_rel  = (const float*)d_in[3];
    const float* b1      = (const float*)d_in[4];
    const float* W1_root = (const float*)d_in[5];
    const float* W2_rel  = (const float*)d_in[6];
    const float* b2      = (const float*)d_in[7];
    const float* W2_root = (const float*)d_in[8];
    const float* W3_rel  = (const float*)d_in[9];
    const float* b3      = (const float*)d_in[10];
    const float* W3_root = (const float*)d_in[11];
    const float* W4_rel  = (const float*)d_in[12];
    const float* b4      = (const float*)d_in[13];
    const float* W4_root = (const float*)d_in[14];
    const float* fc1_w = (const float*)d_in[15];
    const float* fc1_b = (const float*)d_in[16];
    const float* fc2_w = (const float*)d_in[17];
    const float* fc2_b = (const float*)d_in[18];
    const float* fc3_w = (const float*)d_in[19];
    const float* fc3_b = (const float*)d_in[20];
    const float* fc4_w = (const float*)d_in[21];
    const float* fc4_b = (const float*)d_in[22];
    float* out = (float*)d_out;

    // ---- workspace layout (float units): fp32 P and Q node buffers + CSR ----
    size_t fN  = (size_t)N * HID;
    size_t off_P      = 0;
    size_t off_Q      = off_P + fN;
    size_t off_gpool  = off_Q + fN;
    size_t off_t1     = off_gpool + (size_t)G * 1024;
    size_t off_t2     = off_t1 + (size_t)G * HID;
    size_t off_ei     = off_t2 + (size_t)G * HID;          // 2E ints
    size_t off_batch  = off_ei + (size_t)2 * E;            // N ints
    size_t off_starts = off_batch + (size_t)N;             // G+1 ints
    size_t off_flag   = off_starts + (size_t)(G + 1);      // 1 int
    size_t off_deg    = off_flag + 1;                      // N ints
    size_t off_cur    = off_deg + (size_t)N;               // N ints
    size_t off_rowp   = off_cur + (size_t)N;               // N+1 ints
    size_t off_bsum   = off_rowp + (size_t)(N + 1);        // 1024 ints
    size_t off_esrc   = off_bsum + 1024;                   // E ints
    size_t off_wsplit = (off_esrc + (size_t)E + 3) & ~(size_t)3;  // 16B-align
    size_t need = (off_wsplit + 393216 + 16) * 4;          // ~230 MB

    if (ws_size < need) {
        fprintf(stderr, "[kernel_launch] ws too small: ws=%zu need=%zu\n", ws_size, need);
        marker_k<<<(G + 255) / 256, 256, 0, stream>>>(out, G, (float)(ws_size >> 20));
        return;
    }

    float* wsf   = (float*)d_ws;
    float* P     = wsf + off_P;
    float* Q     = wsf + off_Q;
    float* gpool = wsf + off_gpool;
    float* t1    = wsf + off_t1;
    float* t2    = wsf + off_t2;
    int* nei     = (int*)(wsf + off_ei);
    int* nbatch  = (int*)(wsf + off_batch);
    int* starts  = (int*)(wsf + off_starts);
    int* flag    = (int*)(wsf + off_flag);
    int* deg     = (int*)(wsf + off_deg);
    int* cursor  = (int*)(wsf + off_cur);
    int* row_ptr = (int*)(wsf + off_rowp);
    int* bsum    = (int*)(wsf + off_bsum);
    int* esrc    = (int*)(wsf + off_esrc);
    unsigned short* wsplit = (unsigned short*)(wsf + off_wsplit);

    // ---- normalize index dtype (int64 vs int32) on-device ----
    hipMemsetAsync(flag, 0, sizeof(int), stream);
    detect64_k<<<1024, 256, 0, stream>>>((const unsigned*)ei_raw, E,
                                         (const unsigned*)b_raw, N / 2, flag);
    norm_idx_k<<<1024, 256, 0, stream>>>(ei_raw, nei, 2 * E, flag);
    norm_idx_k<<<512, 256, 0, stream>>>(b_raw, nbatch, N, flag);

    pool_bounds_k<<<(G + 1 + 255) / 256, 256, 0, stream>>>(nbatch, N, G, starts);

    // ---- build CSR by destination ----
    hipMemsetAsync(deg, 0, 2 * (size_t)N * sizeof(int), stream);
    deg_count_k<<<(E + 255) / 256, 256, 0, stream>>>(nei, E, N, deg);
    int nb = (N + 1 + SCAN_BLK - 1) / SCAN_BLK;
    if (nb <= 1024) {
        scan_a_k<<<nb, SCAN_BLK, 0, stream>>>(deg, bsum, N);
        scan_b_k<<<1, 1024, 0, stream>>>(bsum, nb);
        scan_c_k<<<nb, SCAN_BLK, 0, stream>>>(deg, bsum, row_ptr, N);
    } else {
        scan_rowptr_k<<<1, 1024, 0, stream>>>(deg, row_ptr, N);
    }
    fill_csr_k<<<(E + 255) / 256, 256, 0, stream>>>(nei, E, N, row_ptr, cursor, esrc);

    // ---- pre-split GraphConv weights (chunk-major, swizzled layout) ----
    wsplit6_k<<<dim3((65536 + 255) / 256, 6), 256, 0, stream>>>(
        W2_rel, W2_root, W3_rel, W3_root, W4_rel, W4_root, wsplit, 65536);

    int nstrips = (N + 63) / 64;

    // ---- layer 1: gather 28-wide into Q prefix, fused GEMM -> P ----
    gather28_k<<<((size_t)N * 32 + 255) / 256, 256, 0, stream>>>(x, row_ptr, esrc, Q, N);
    l1_fused_k<<<nstrips, 256, 0, stream>>>(x, Q, W1_rel, W1_root, b1, P, N);
    pool_slice_k<<<G, 256, 0, stream>>>(P, starts, gpool + 0, N);

    // ---- layers 2..4: gather P->Q; MFMA strip GEMM in-place on P; pool ----
    const float* bb[3] = {b2, b3, b4};
    for (int l = 0; l < 3; l++) {
        gather256_k<<<((size_t)N * 64 + 255) / 256, 256, 0, stream>>>(P, row_ptr, esrc, Q, N);
        gemm_strip_mfma_k<<<nstrips, 256, 0, stream>>>(
            Q, wsplit + (size_t)(2 * l) * 131072,
            P, wsplit + (size_t)(2 * l + 1) * 131072, bb[l], N);
        pool_slice_k<<<G, 256, 0, stream>>>(P, starts, gpool + 256 * (l + 1), N);
    }

    // ---- MLP head ----
    dim3 gdimG(G / BM, HID / BN);
    gemm_dual_k<<<gdimG, 256, 0, stream>>>(gpool, 1024, fc1_w, nullptr, 0, nullptr,
                                           fc1_b, t1, HID, G, 1024, 0, 1);
    gemm_dual_k<<<gdimG, 256, 0, stream>>>(t1, HID, fc2_w, nullptr, 0, nullptr,
                                           fc2_b, t2, HID, G, HID, 0, 1);
    gemm_dual_k<<<gdimG, 256, 0, stream>>>(t2, HID, fc3_w, nullptr, 0, nullptr,
                                           fc3_b, t1, HID, G, HID, 0, 1);
    fc4_k<<<(G * 64 + 255) / 256, 256, 0, stream>>>(t1, fc4_w, fc4_b, out, G);
}

// Round 21
// 895.856 us; speedup vs baseline: 1.1760x; 1.0649x over previous
//
#include <hip/hip_runtime.h>
#include <hip/hip_bf16.h>
#include <cstdio>

#define HID 256

using short8  = __attribute__((ext_vector_type(8))) short;
using floatx4 = __attribute__((ext_vector_type(4))) float;

typedef const unsigned int __attribute__((address_space(1)))* as1_cuintp;
typedef unsigned int __attribute__((address_space(3)))* as3_uintp;

__device__ inline unsigned short bf16_rn(float x) {
    unsigned u = __float_as_uint(x);
    return (unsigned short)((u + 0x7FFFu + ((u >> 16) & 1u)) >> 16);
}
__device__ inline float bf2f(unsigned short u) {
    return __uint_as_float(((unsigned)u) << 16);
}

// ---------------- diagnostic marker (ws too small) ----------------
__global__ void marker_k(float* __restrict__ out, int n, float v) {
    int i = blockIdx.x * blockDim.x + threadIdx.x;
    if (i < n) out[i] = v;
}

// ---------------- int64-vs-int32 detection ----------------
__global__ void detect64_k(const unsigned* __restrict__ eiw, int E,
                           const unsigned* __restrict__ bw, int Nh,
                           int* __restrict__ any_nonzero) {
    int total = E + Nh;
    unsigned loc = 0;
    for (int i = blockIdx.x * blockDim.x + threadIdx.x; i < total;
         i += gridDim.x * blockDim.x) {
        loc |= (i < E) ? eiw[2 * i + 1] : bw[2 * (i - E) + 1];
    }
    if (loc) atomicOr(any_nonzero, 1);
}

__global__ void norm_idx_k(const int* __restrict__ src, int* __restrict__ dst,
                           int n, const int* __restrict__ any_nonzero) {
    int is64 = (any_nonzero[0] == 0);
    for (int i = blockIdx.x * blockDim.x + threadIdx.x; i < n;
         i += gridDim.x * blockDim.x) {
        dst[i] = is64 ? src[2 * i] : src[i];
    }
}

// ---------------- graph boundaries (batch is sorted) ----------------
__global__ void pool_bounds_k(const int* __restrict__ batch, int N, int G,
                              int* __restrict__ starts) {
    int g = blockIdx.x * blockDim.x + threadIdx.x;
    if (g > G) return;
    int lo = 0, hi = N;
    while (lo < hi) {
        int mid = (lo + hi) >> 1;
        if (batch[mid] < g) lo = mid + 1; else hi = mid;
    }
    starts[g] = lo;
}

// ---------------- CSR build ----------------
__global__ void deg_count_k(const int* __restrict__ ei, int E, int N,
                            int* __restrict__ deg) {
    int e = blockIdx.x * blockDim.x + threadIdx.x;
    if (e >= E) return;
    int s = ei[e];
    int d = ei[E + e];
    if ((unsigned)s >= (unsigned)N || (unsigned)d >= (unsigned)N) return;
    atomicAdd(&deg[d], 1);
}

// ---- two-level grid-wide exclusive scan ----
#define SCAN_BLK 256

__global__ __launch_bounds__(SCAN_BLK) void scan_a_k(const int* __restrict__ deg,
                                                     int* __restrict__ bsum, int N) {
    __shared__ int red[SCAN_BLK];
    int i = blockIdx.x * SCAN_BLK + threadIdx.x;
    int v = (i < N) ? deg[i] : 0;
    red[threadIdx.x] = v;
    __syncthreads();
#pragma unroll
    for (int off = SCAN_BLK / 2; off > 0; off >>= 1) {
        if (threadIdx.x < off) red[threadIdx.x] += red[threadIdx.x + off];
        __syncthreads();
    }
    if (threadIdx.x == 0) bsum[blockIdx.x] = red[0];
}

__global__ __launch_bounds__(1024) void scan_b_k(int* __restrict__ bsum, int nb) {
    __shared__ int tsum[1024];
    int t = threadIdx.x;
    int v = (t < nb) ? bsum[t] : 0;
    tsum[t] = v;
    __syncthreads();
    for (int off = 1; off < 1024; off <<= 1) {
        int u = (t >= off) ? tsum[t - off] : 0;
        __syncthreads();
        tsum[t] += u;
        __syncthreads();
    }
    if (t < nb) bsum[t] = tsum[t] - v;
}

__global__ __launch_bounds__(SCAN_BLK) void scan_c_k(const int* __restrict__ deg,
                                                     const int* __restrict__ bsum,
                                                     int* __restrict__ row_ptr, int N) {
    __shared__ int tsum[SCAN_BLK];
    int t = threadIdx.x;
    int i = blockIdx.x * SCAN_BLK + t;
    int v = (i < N) ? deg[i] : 0;
    tsum[t] = v;
    __syncthreads();
    for (int off = 1; off < SCAN_BLK; off <<= 1) {
        int u = (t >= off) ? tsum[t - off] : 0;
        __syncthreads();
        tsum[t] += u;
        __syncthreads();
    }
    if (i <= N) row_ptr[i] = tsum[t] - v + bsum[blockIdx.x];
}

__global__ __launch_bounds__(1024) void scan_rowptr_k(const int* __restrict__ deg,
                                                      int* __restrict__ row_ptr, int N) {
    __shared__ int tsum[1024];
    int t = threadIdx.x;
    int chunk = (N + 1023) / 1024;
    int lo = t * chunk;
    int hi = min(lo + chunk, N);
    int s = 0;
    for (int i = lo; i < hi; i++) s += deg[i];
    tsum[t] = s;
    __syncthreads();
    for (int off = 1; off < 1024; off <<= 1) {
        int v = (t >= off) ? tsum[t - off] : 0;
        __syncthreads();
        tsum[t] += v;
        __syncthreads();
    }
    int run = (t == 0) ? 0 : tsum[t - 1];
    for (int i = lo; i < hi; i++) { row_ptr[i] = run; run += deg[i]; }
    if (hi >= N && lo <= N) row_ptr[N] = run;
}

__global__ void fill_csr_k(const int* __restrict__ ei, int E, int N,
                           const int* __restrict__ row_ptr, int* __restrict__ cursor,
                           int* __restrict__ esrc) {
    int e = blockIdx.x * blockDim.x + threadIdx.x;
    if (e >= E) return;
    int s = ei[e];
    int d = ei[E + e];
    if ((unsigned)s >= (unsigned)N || (unsigned)d >= (unsigned)N) return;
    int pos = atomicAdd(&cursor[d], 1);
    esrc[row_ptr[d] + pos] = s;
}

// ---------------- pad x (N x 28) -> X32 (N x 32, zero-padded) ----------------
__global__ void pad_x_k(const float* __restrict__ x, float* __restrict__ X32, int N) {
    int i = blockIdx.x * blockDim.x + threadIdx.x;
    if (i >= N * 32) return;
    int node = i >> 5;
    int lane = i & 31;
    X32[i] = (lane < 28) ? x[(size_t)node * 28 + lane] : 0.f;
}

// ---------------- gather aggregation, 28-wide -> Q32 (zero-padded) ----------------
__global__ void gather28_k(const float* __restrict__ x, const int* __restrict__ row_ptr,
                           const int* __restrict__ esrc, float* __restrict__ Q32, int N) {
    int gid = blockIdx.x * blockDim.x + threadIdx.x;
    int node = gid >> 5;
    if (node >= N) return;
    int lane = gid & 31;
    float acc = 0.f;
    if (lane < 28) {
        int s = row_ptr[node], e = row_ptr[node + 1];
        for (int i = s; i < e; i++) {
            int src = esrc[i];
            acc += x[(size_t)src * 28 + lane];
        }
    }
    Q32[(size_t)node * 32 + lane] = acc;
}

// ---------------- gather aggregation, 256-wide (plain fp32) ----------------
__global__ void gather256_k(const float* __restrict__ P, const int* __restrict__ row_ptr,
                            const int* __restrict__ esrc, float* __restrict__ Q, int N) {
    int gid = blockIdx.x * blockDim.x + threadIdx.x;
    int node = gid >> 6;
    if (node >= N) return;
    int lane = gid & 63;
    int s = row_ptr[node], e = row_ptr[node + 1];
    float4 acc = make_float4(0.f, 0.f, 0.f, 0.f);
    for (int i = s; i < e; i++) {
        int src = esrc[i];
        float4 v = *(const float4*)(P + (size_t)src * HID + lane * 4);
        acc.x += v.x; acc.y += v.y; acc.z += v.z; acc.w += v.w;
    }
    *(float4*)(Q + (size_t)node * HID + lane * 4) = acc;
}

// ---------------- weight split (layers 2-4): chunk-major swizzled layout ----------------
__global__ void wsplit6_k(const float* W0, const float* W1, const float* W2,
                          const float* W3, const float* W4, const float* W5,
                          unsigned short* __restrict__ out_hl, int n) {
    int i = blockIdx.x * blockDim.x + threadIdx.x;
    if (i >= n) return;
    const float* W = (blockIdx.y == 0) ? W0 : (blockIdx.y == 1) ? W1 :
                     (blockIdx.y == 2) ? W2 : (blockIdx.y == 3) ? W3 :
                     (blockIdx.y == 4) ? W4 : W5;
    unsigned short* o = out_hl + (size_t)blockIdx.y * 131072;
    float a = W[i];
    unsigned short h = bf16_rn(a);
    unsigned short lo = bf16_rn(a - bf2f(h));
    int col = i >> 8;
    int k   = i & 255;
    int ch  = k >> 5;
    int sg  = (k >> 3) & 3;
    int e   = k & 7;
    int gp  = sg ^ ((col >> 1) & 3);
    size_t base = (size_t)ch * 16384 + (size_t)col * 32 + gp * 8 + e;
    o[base] = h;
    o[base + 8192] = lo;
}

// ---------------- weight split (layer 1): W1_rel/W1_root 256x28 -> padded K=32 ----------------
__global__ void wsplit1_k(const float* __restrict__ W0, const float* __restrict__ W1,
                          unsigned short* __restrict__ o) {
    int i = blockIdx.x * blockDim.x + threadIdx.x;
    if (i >= 2 * 8192) return;
    int m   = i >> 13;
    int r   = i & 8191;       // col*32 + k
    int col = r >> 5;
    int k   = r & 31;
    const float* W = m ? W1 : W0;
    float a = (k < 28) ? W[col * 28 + k] : 0.f;
    unsigned short h = bf16_rn(a);
    unsigned short lo = bf16_rn(a - bf2f(h));
    int sg = (k >> 3) & 3;
    int e  = k & 7;
    int gp = sg ^ ((col >> 1) & 3);
    size_t base = (size_t)m * 16384 + (size_t)col * 32 + gp * 8 + e;
    o[base] = h;
    o[base + 8192] = lo;
}

// ---------------- layer-1 MFMA GEMM: 2 chunks (agg32, x32), K=32 each ----------------
#define LSTR 40

__global__ __launch_bounds__(256) void l1_mfma_k(
    const float* __restrict__ Q32, const unsigned short* __restrict__ Wrel_hl,
    const float* __restrict__ X32, const unsigned short* __restrict__ Wroot_hl,
    const float* __restrict__ bias, float* __restrict__ P, int M) {
    __shared__ __attribute__((aligned(16))) unsigned short Ah[64 * LSTR];
    __shared__ __attribute__((aligned(16))) unsigned short Al[64 * LSTR];
    __shared__ __attribute__((aligned(16))) unsigned short Wbuf[8192];
    int t = threadIdx.x;
    int brow = blockIdx.x * 64;
    int w = t >> 6;
    int l = t & 63;

    floatx4 acc[4][4];
#pragma unroll
    for (int i = 0; i < 4; i++)
#pragma unroll
        for (int j = 0; j < 4; j++) acc[i][j] = (floatx4){0.f, 0.f, 0.f, 0.f};

    int srow = t >> 2;
    int sg   = t & 3;

#pragma unroll
    for (int ch = 0; ch < 2; ch++) {
        const float* A = ch ? X32 : Q32;
        const unsigned short* Whl = ch ? Wroot_hl : Wrel_hl;

        {
            const char* wg = (const char*)Whl + w * 4096;
            char* ld = (char*)Wbuf + w * 4096;
#pragma unroll
            for (int i = 0; i < 4; i++) {
                __builtin_amdgcn_global_load_lds(
                    (as1_cuintp)(const void*)(wg + i * 1024 + l * 16),
                    (as3_uintp)(void*)(ld + i * 1024),
                    16, 0, 0);
            }
        }
        {
            int gr = brow + srow;
            float v[8];
            if (gr < M) {
                float4 u0 = *(const float4*)(A + (size_t)gr * 32 + sg * 8);
                float4 u1 = *(const float4*)(A + (size_t)gr * 32 + sg * 8 + 4);
                v[0] = u0.x; v[1] = u0.y; v[2] = u0.z; v[3] = u0.w;
                v[4] = u1.x; v[5] = u1.y; v[6] = u1.z; v[7] = u1.w;
            } else {
#pragma unroll
                for (int j = 0; j < 8; j++) v[j] = 0.f;
            }
            union { unsigned short us[8]; short8 v8; } hh, ll;
#pragma unroll
            for (int j = 0; j < 8; j++) {
                unsigned short h = bf16_rn(v[j]);
                float hf = bf2f(h);
                hh.us[j] = h;
                ll.us[j] = bf16_rn(v[j] - hf);
            }
            int base = srow * LSTR + sg * 8;
            *(short8*)(Ah + base) = hh.v8;
            *(short8*)(Al + base) = ll.v8;
        }
        __syncthreads();

        int frow = l & 15;
        int fg   = l >> 4;
        short8 ahf[4], alf[4], wf[4];
#pragma unroll
        for (int rt = 0; rt < 4; rt++) {
            int base = (rt * 16 + frow) * LSTR + fg * 8;
            ahf[rt] = *(short8*)(Ah + base);
            alf[rt] = *(short8*)(Al + base);
        }
#pragma unroll
        for (int ct = 0; ct < 4; ct++) {
            int col = w * 64 + ct * 16 + frow;
            int gp = fg ^ ((col >> 1) & 3);
            wf[ct] = *(short8*)(Wbuf + col * 32 + gp * 8);
        }
        asm volatile("s_waitcnt lgkmcnt(0)" ::: "memory");
        __builtin_amdgcn_sched_barrier(0);
        {
            const char* wg = (const char*)(Whl + 8192) + w * 4096;
            char* ld = (char*)Wbuf + w * 4096;
#pragma unroll
            for (int i = 0; i < 4; i++) {
                __builtin_amdgcn_global_load_lds(
                    (as1_cuintp)(const void*)(wg + i * 1024 + l * 16),
                    (as3_uintp)(void*)(ld + i * 1024),
                    16, 0, 0);
            }
        }
        __builtin_amdgcn_s_setprio(1);
#pragma unroll
        for (int rt = 0; rt < 4; rt++)
#pragma unroll
            for (int ct = 0; ct < 4; ct++) {
                acc[rt][ct] = __builtin_amdgcn_mfma_f32_16x16x32_bf16(
                    ahf[rt], wf[ct], acc[rt][ct], 0, 0, 0);
                acc[rt][ct] = __builtin_amdgcn_mfma_f32_16x16x32_bf16(
                    alf[rt], wf[ct], acc[rt][ct], 0, 0, 0);
            }
        __builtin_amdgcn_s_setprio(0);
        asm volatile("s_waitcnt vmcnt(0)" ::: "memory");
        __builtin_amdgcn_sched_barrier(0);
#pragma unroll
        for (int ct = 0; ct < 4; ct++) {
            int col = w * 64 + ct * 16 + frow;
            int gp = fg ^ ((col >> 1) & 3);
            wf[ct] = *(short8*)(Wbuf + col * 32 + gp * 8);
        }
        __builtin_amdgcn_s_setprio(1);
#pragma unroll
        for (int rt = 0; rt < 4; rt++)
#pragma unroll
            for (int ct = 0; ct < 4; ct++)
                acc[rt][ct] = __builtin_amdgcn_mfma_f32_16x16x32_bf16(
                    ahf[rt], wf[ct], acc[rt][ct], 0, 0, 0);
        __builtin_amdgcn_s_setprio(0);
        __syncthreads();
    }

#pragma unroll
    for (int ct = 0; ct < 4; ct++) {
        int gc = w * 64 + ct * 16 + (l & 15);
        float bs = bias[gc];
#pragma unroll
        for (int rt = 0; rt < 4; rt++) {
            floatx4 a = acc[rt][ct];
#pragma unroll
            for (int r = 0; r < 4; r++) {
                int gr = brow + rt * 16 + (l >> 4) * 4 + r;
                if (gr < M)
                    P[(size_t)gr * HID + gc] = fmaxf(a[r] + bs, 0.f);
            }
        }
    }
}

// ---------------- MFMA strip GEMM (round-19: single-plane W + setprio) ----------------
__global__ __launch_bounds__(256) void gemm_strip_mfma_k(
    const float* __restrict__ Q, const unsigned short* __restrict__ Wr_hl,
    float* __restrict__ P, const unsigned short* __restrict__ Wo_hl,
    const float* __restrict__ bias, int M) {
    __shared__ __attribute__((aligned(16))) unsigned short Ah[64 * LSTR];
    __shared__ __attribute__((aligned(16))) unsigned short Al[64 * LSTR];
    __shared__ __attribute__((aligned(16))) unsigned short Wbuf[8192];
    int t = threadIdx.x;
    int brow = blockIdx.x * 64;
    int w = t >> 6;
    int l = t & 63;

    floatx4 acc[4][4];
#pragma unroll
    for (int i = 0; i < 4; i++)
#pragma unroll
        for (int j = 0; j < 4; j++) acc[i][j] = (floatx4){0.f, 0.f, 0.f, 0.f};

    int srow = t >> 2;
    int sg   = t & 3;

    for (int ch = 0; ch < 16; ch++) {
        int phase2 = (ch >= 8);
        const float* A = phase2 ? P : Q;
        const unsigned short* Whl = phase2 ? Wo_hl : Wr_hl;
        int kbase = (ch & 7) * 32;

        {
            const char* wg = (const char*)(Whl + (size_t)(ch & 7) * 16384) + w * 4096;
            char* ld = (char*)Wbuf + w * 4096;
#pragma unroll
            for (int i = 0; i < 4; i++) {
                __builtin_amdgcn_global_load_lds(
                    (as1_cuintp)(const void*)(wg + i * 1024 + l * 16),
                    (as3_uintp)(void*)(ld + i * 1024),
                    16, 0, 0);
            }
        }
        {
            int gr = brow + srow;
            float v[8];
            if (gr < M) {
                float4 u0 = *(const float4*)(A + (size_t)gr * HID + kbase + sg * 8);
                float4 u1 = *(const float4*)(A + (size_t)gr * HID + kbase + sg * 8 + 4);
                v[0] = u0.x; v[1] = u0.y; v[2] = u0.z; v[3] = u0.w;
                v[4] = u1.x; v[5] = u1.y; v[6] = u1.z; v[7] = u1.w;
            } else {
#pragma unroll
                for (int j = 0; j < 8; j++) v[j] = 0.f;
            }
            union { unsigned short us[8]; short8 v8; } hh, ll;
#pragma unroll
            for (int j = 0; j < 8; j++) {
                unsigned short h = bf16_rn(v[j]);
                float hf = bf2f(h);
                hh.us[j] = h;
                ll.us[j] = bf16_rn(v[j] - hf);
            }
            int base = srow * LSTR + sg * 8;
            *(short8*)(Ah + base) = hh.v8;
            *(short8*)(Al + base) = ll.v8;
        }
        __syncthreads();

        int frow = l & 15;
        int fg   = l >> 4;
        short8 ahf[4], alf[4], wf[4];
#pragma unroll
        for (int rt = 0; rt < 4; rt++) {
            int base = (rt * 16 + frow) * LSTR + fg * 8;
            ahf[rt] = *(short8*)(Ah + base);
            alf[rt] = *(short8*)(Al + base);
        }
#pragma unroll
        for (int ct = 0; ct < 4; ct++) {
            int col = w * 64 + ct * 16 + frow;
            int gp = fg ^ ((col >> 1) & 3);
            wf[ct] = *(short8*)(Wbuf + col * 32 + gp * 8);
        }
        asm volatile("s_waitcnt lgkmcnt(0)" ::: "memory");
        __builtin_amdgcn_sched_barrier(0);
        {
            const char* wg = (const char*)(Whl + (size_t)(ch & 7) * 16384 + 8192) + w * 4096;
            char* ld = (char*)Wbuf + w * 4096;
#pragma unroll
            for (int i = 0; i < 4; i++) {
                __builtin_amdgcn_global_load_lds(
                    (as1_cuintp)(const void*)(wg + i * 1024 + l * 16),
                    (as3_uintp)(void*)(ld + i * 1024),
                    16, 0, 0);
            }
        }
        __builtin_amdgcn_s_setprio(1);
#pragma unroll
        for (int rt = 0; rt < 4; rt++)
#pragma unroll
            for (int ct = 0; ct < 4; ct++) {
                acc[rt][ct] = __builtin_amdgcn_mfma_f32_16x16x32_bf16(
                    ahf[rt], wf[ct], acc[rt][ct], 0, 0, 0);
                acc[rt][ct] = __builtin_amdgcn_mfma_f32_16x16x32_bf16(
                    alf[rt], wf[ct], acc[rt][ct], 0, 0, 0);
            }
        __builtin_amdgcn_s_setprio(0);
        asm volatile("s_waitcnt vmcnt(0)" ::: "memory");
        __builtin_amdgcn_sched_barrier(0);
#pragma unroll
        for (int ct = 0; ct < 4; ct++) {
            int col = w * 64 + ct * 16 + frow;
            int gp = fg ^ ((col >> 1) & 3);
            wf[ct] = *(short8*)(Wbuf + col * 32 + gp * 8);
        }
        __builtin_amdgcn_s_setprio(1);
#pragma unroll
        for (int rt = 0; rt < 4; rt++)
#pragma unroll
            for (int ct = 0; ct < 4; ct++)
                acc[rt][ct] = __builtin_amdgcn_mfma_f32_16x16x32_bf16(
                    ahf[rt], wf[ct], acc[rt][ct], 0, 0, 0);
        __builtin_amdgcn_s_setprio(0);
        __syncthreads();
    }

#pragma unroll
    for (int ct = 0; ct < 4; ct++) {
        int gc = w * 64 + ct * 16 + (l & 15);
        float bs = bias[gc];
#pragma unroll
        for (int rt = 0; rt < 4; rt++) {
            floatx4 a = acc[rt][ct];
#pragma unroll
            for (int r = 0; r < 4; r++) {
                int gr = brow + rt * 16 + (l >> 4) * 4 + r;
                if (gr < M)
                    P[(size_t)gr * HID + gc] = fmaxf(a[r] + bs, 0.f);
            }
        }
    }
}

// ---------------- per-layer mean-pool slice ----------------
__global__ __launch_bounds__(256) void pool_slice_k(const float* __restrict__ xl,
                                                    const int* __restrict__ starts,
                                                    float* __restrict__ gslice, int N) {
    int g = blockIdx.x;
    int t = threadIdx.x;
    int s = starts[g], e = starts[g + 1];
    s = max(0, min(s, N));
    e = max(s, min(e, N));
    float a = 0.f;
    for (int n = s; n < e; n++) a += xl[(size_t)n * HID + t];
    float inv = 1.f / (float)max(e - s, 1);
    gslice[(size_t)g * 1024 + t] = a * inv;
}

// ---------------- out-of-place dual GEMM (MLP head, fp32) ----------------
#define BM 64
#define BN 64
#define BK 32
#define LP 68

__global__ __launch_bounds__(256) void gemm_dual_k(
    const float* __restrict__ A1, int lda1, const float* __restrict__ W1,
    const float* __restrict__ A2, int lda2, const float* __restrict__ W2,
    const float* __restrict__ bias, float* __restrict__ out, int ldout,
    int M, int K1, int K2, int relu) {
    __shared__ float As[BK][LP];
    __shared__ float Ws[BK][LP];
    int t = threadIdx.x;
    int brow = blockIdx.x * BM;
    int bcol = blockIdx.y * BN;
    int tx = t & 15, ty = t >> 4;
    float acc[4][4] = {{0.f}};
    int Ktot = K1 + K2;
    int srow = t >> 3;
    int sk4 = (t & 7) << 2;

    for (int kk = 0; kk < Ktot; kk += BK) {
        int phase2 = (kk >= K1);
        const float* A = phase2 ? A2 : A1;
        const float* W = phase2 ? W2 : W1;
        int lda = phase2 ? lda2 : lda1;
        int ldw = phase2 ? K2 : K1;
        int kbase = phase2 ? (kk - K1) : kk;
#pragma unroll
        for (int i = 0; i < 2; i++) {
            int r = srow + i * 32;
            int gr = brow + r;
            float4 v = make_float4(0.f, 0.f, 0.f, 0.f);
            if (gr < M) v = *(const float4*)(A + (size_t)gr * lda + kbase + sk4);
            As[sk4 + 0][r] = v.x; As[sk4 + 1][r] = v.y;
            As[sk4 + 2][r] = v.z; As[sk4 + 3][r] = v.w;
            float4 w = *(const float4*)(W + (size_t)(bcol + r) * ldw + kbase + sk4);
            Ws[sk4 + 0][r] = w.x; Ws[sk4 + 1][r] = w.y;
            Ws[sk4 + 2][r] = w.z; Ws[sk4 + 3][r] = w.w;
        }
        __syncthreads();
#pragma unroll
        for (int k = 0; k < BK; k++) {
            float4 a = *(const float4*)&As[k][ty << 2];
            float4 w = *(const float4*)&Ws[k][tx << 2];
            float av[4] = {a.x, a.y, a.z, a.w};
            float wv[4] = {w.x, w.y, w.z, w.w};
#pragma unroll
            for (int i = 0; i < 4; i++)
#pragma unroll
                for (int j = 0; j < 4; j++)
                    acc[i][j] = fmaf(av[i], wv[j], acc[i][j]);
        }
        __syncthreads();
    }
#pragma unroll
    for (int i = 0; i < 4; i++) {
        int gr = brow + (ty << 2) + i;
        if (gr >= M) continue;
#pragma unroll
        for (int j = 0; j < 4; j++) {
            int gc = bcol + (tx << 2) + j;
            float v = acc[i][j] + bias[gc];
            if (relu) v = fmaxf(v, 0.f);
            out[(size_t)gr * ldout + gc] = v;
        }
    }
}

// ---------------- fc4 ----------------
__global__ void fc4_k(const float* __restrict__ in, const float* __restrict__ w,
                      const float* __restrict__ b, float* __restrict__ out, int M) {
    int gid = blockIdx.x * blockDim.x + threadIdx.x;
    int row = gid >> 6;
    if (row >= M) return;
    int lane = gid & 63;
    float4 v  = *(const float4*)(in + (size_t)row * HID + lane * 4);
    float4 ww = *(const float4*)(w + lane * 4);
    float acc = v.x * ww.x + v.y * ww.y + v.z * ww.z + v.w * ww.w;
#pragma unroll
    for (int off = 32; off; off >>= 1) acc += __shfl_down(acc, off);
    if (lane == 0) out[row] = acc + b[0];
}

extern "C" void kernel_launch(void* const* d_in, const int* in_sizes, int n_in,
                              void* d_out, int out_size, void* d_ws, size_t ws_size,
                              hipStream_t stream) {
    const int N = in_sizes[0] / 28;       // 100000
    const int E = in_sizes[1] / 2;        // 320000
    const int G = out_size;               // 4096

    const float* x        = (const float*)d_in[0];
    const int*   ei_raw   = (const int*)d_in[1];
    const int*   b_raw    = (const int*)d_in[2];
    const float* W1_rel  = (const float*)d_in[3];
    const float* b1      = (const float*)d_in[4];
    const float* W1_root = (const float*)d_in[5];
    const float* W2_rel  = (const float*)d_in[6];
    const float* b2      = (const float*)d_in[7];
    const float* W2_root = (const float*)d_in[8];
    const float* W3_rel  = (const float*)d_in[9];
    const float* b3      = (const float*)d_in[10];
    const float* W3_root = (const float*)d_in[11];
    const float* W4_rel  = (const float*)d_in[12];
    const float* b4      = (const float*)d_in[13];
    const float* W4_root = (const float*)d_in[14];
    const float* fc1_w = (const float*)d_in[15];
    const float* fc1_b = (const float*)d_in[16];
    const float* fc2_w = (const float*)d_in[17];
    const float* fc2_b = (const float*)d_in[18];
    const float* fc3_w = (const float*)d_in[19];
    const float* fc3_b = (const float*)d_in[20];
    const float* fc4_w = (const float*)d_in[21];
    const float* fc4_b = (const float*)d_in[22];
    float* out = (float*)d_out;

    // ---- workspace layout (float units) ----
    size_t fN  = (size_t)N * HID;
    size_t off_P      = 0;
    size_t off_Q      = off_P + fN;
    size_t off_gpool  = off_Q + fN;
    size_t off_t1     = off_gpool + (size_t)G * 1024;
    size_t off_t2     = off_t1 + (size_t)G * HID;
    size_t off_ei     = off_t2 + (size_t)G * HID;          // 2E ints
    size_t off_batch  = off_ei + (size_t)2 * E;            // N ints
    size_t off_starts = off_batch + (size_t)N;             // G+1 ints
    size_t off_flag   = off_starts + (size_t)(G + 1);      // 1 int
    size_t off_deg    = off_flag + 1;                      // N ints
    size_t off_cur    = off_deg + (size_t)N;               // N ints
    size_t off_rowp   = off_cur + (size_t)N;               // N+1 ints
    size_t off_bsum   = off_rowp + (size_t)(N + 1);        // 1024 ints
    size_t off_esrc   = off_bsum + 1024;                   // E ints
    size_t off_wsplit = (off_esrc + (size_t)E + 3) & ~(size_t)3;   // 6x131072 ushorts = 393216 floats
    size_t off_w1     = off_wsplit + 393216;                       // 2x16384 ushorts = 16384 floats
    size_t off_X32    = (off_w1 + 16384 + 3) & ~(size_t)3;         // N*32 floats
    size_t off_Q32    = off_X32 + (size_t)N * 32;                  // N*32 floats
    size_t need = (off_Q32 + (size_t)N * 32 + 16) * 4;             // ~263 MB

    if (ws_size < need) {
        fprintf(stderr, "[kernel_launch] ws too small: ws=%zu need=%zu\n", ws_size, need);
        marker_k<<<(G + 255) / 256, 256, 0, stream>>>(out, G, (float)(ws_size >> 20));
        return;
    }

    float* wsf   = (float*)d_ws;
    float* P     = wsf + off_P;
    float* Q     = wsf + off_Q;
    float* gpool = wsf + off_gpool;
    float* t1    = wsf + off_t1;
    float* t2    = wsf + off_t2;
    int* nei     = (int*)(wsf + off_ei);
    int* nbatch  = (int*)(wsf + off_batch);
    int* starts  = (int*)(wsf + off_starts);
    int* flag    = (int*)(wsf + off_flag);
    int* deg     = (int*)(wsf + off_deg);
    int* cursor  = (int*)(wsf + off_cur);
    int* row_ptr = (int*)(wsf + off_rowp);
    int* bsum    = (int*)(wsf + off_bsum);
    int* esrc    = (int*)(wsf + off_esrc);
    unsigned short* wsplit = (unsigned short*)(wsf + off_wsplit);
    unsigned short* w1split = (unsigned short*)(wsf + off_w1);
    float* X32   = wsf + off_X32;
    float* Q32   = wsf + off_Q32;

    // ---- normalize index dtype (int64 vs int32) on-device ----
    hipMemsetAsync(flag, 0, sizeof(int), stream);
    detect64_k<<<1024, 256, 0, stream>>>((const unsigned*)ei_raw, E,
                                         (const unsigned*)b_raw, N / 2, flag);
    norm_idx_k<<<1024, 256, 0, stream>>>(ei_raw, nei, 2 * E, flag);
    norm_idx_k<<<512, 256, 0, stream>>>(b_raw, nbatch, N, flag);

    pool_bounds_k<<<(G + 1 + 255) / 256, 256, 0, stream>>>(nbatch, N, G, starts);

    // ---- build CSR by destination ----
    hipMemsetAsync(deg, 0, 2 * (size_t)N * sizeof(int), stream);
    deg_count_k<<<(E + 255) / 256, 256, 0, stream>>>(nei, E, N, deg);
    int nb = (N + 1 + SCAN_BLK - 1) / SCAN_BLK;
    if (nb <= 1024) {
        scan_a_k<<<nb, SCAN_BLK, 0, stream>>>(deg, bsum, N);
        scan_b_k<<<1, 1024, 0, stream>>>(bsum, nb);
        scan_c_k<<<nb, SCAN_BLK, 0, stream>>>(deg, bsum, row_ptr, N);
    } else {
        scan_rowptr_k<<<1, 1024, 0, stream>>>(deg, row_ptr, N);
    }
    fill_csr_k<<<(E + 255) / 256, 256, 0, stream>>>(nei, E, N, row_ptr, cursor, esrc);

    // ---- pre-split weights ----
    wsplit6_k<<<dim3((65536 + 255) / 256, 6), 256, 0, stream>>>(
        W2_rel, W2_root, W3_rel, W3_root, W4_rel, W4_root, wsplit, 65536);
    wsplit1_k<<<(2 * 8192 + 255) / 256, 256, 0, stream>>>(W1_rel, W1_root, w1split);

    int nstrips = (N + 63) / 64;

    // ---- layer 1: pad x, gather agg into Q32, MFMA GEMM -> P ----
    pad_x_k<<<((size_t)N * 32 + 255) / 256, 256, 0, stream>>>(x, X32, N);
    gather28_k<<<((size_t)N * 32 + 255) / 256, 256, 0, stream>>>(x, row_ptr, esrc, Q32, N);
    l1_mfma_k<<<nstrips, 256, 0, stream>>>(Q32, w1split, X32, w1split + 16384, b1, P, N);
    pool_slice_k<<<G, 256, 0, stream>>>(P, starts, gpool + 0, N);

    // ---- layers 2..4: gather P->Q; MFMA strip GEMM in-place on P; pool ----
    const float* bb[3] = {b2, b3, b4};
    for (int l = 0; l < 3; l++) {
        gather256_k<<<((size_t)N * 64 + 255) / 256, 256, 0, stream>>>(P, row_ptr, esrc, Q, N);
        gemm_strip_mfma_k<<<nstrips, 256, 0, stream>>>(
            Q, wsplit + (size_t)(2 * l) * 131072,
            P, wsplit + (size_t)(2 * l + 1) * 131072, bb[l], N);
        pool_slice_k<<<G, 256, 0, stream>>>(P, starts, gpool + 256 * (l + 1), N);
    }

    // ---- MLP head ----
    dim3 gdimG(G / BM, HID / BN);
    gemm_dual_k<<<gdimG, 256, 0, stream>>>(gpool, 1024, fc1_w, nullptr, 0, nullptr,
                                           fc1_b, t1, HID, G, 1024, 0, 1);
    gemm_dual_k<<<gdimG, 256, 0, stream>>>(t1, HID, fc2_w, nullptr, 0, nullptr,
                                           fc2_b, t2, HID, G, HID, 0, 1);
    gemm_dual_k<<<gdimG, 256, 0, stream>>>(t2, HID, fc3_w, nullptr, 0, nullptr,
                                           fc3_b, t1, HID, G, HID, 0, 1);
    fc4_k<<<(G * 64 + 255) / 256, 256, 0, stream>>>(t1, fc4_w, fc4_b, out, G);
}